// Round 26
// baseline (141.927 us; speedup 1.0000x reference)
//
#include <hip/hip_runtime.h>
#include <hip/hip_bf16.h>

// Sheaf CNN on the fixed ring graph (offsets ±1..4 mod 4096, degree 8).
// 3-dispatch pipeline, MFMA-K1 edition:
//   K1 (256 thr): ef@[M1w|M1w_hi|We] as bf16 MFMA GEMM (16x16x32), weights
//       staged in LDS with pad-97 rows (conflict-free frag reads); stage-2
//       G=relu(H)@W2 on VALU (f32, numerics = R24). A,B,G -> d_ws.
//   K2: phases 2-4 per 16-node chunk (R24-proven, byte-identical)
//   K3: finalize with Wc1/Wc2 LDS-staged (R24-proven, byte-identical)
// Fused single-dispatch closed (R21/R25: 105us regardless of GEMV impl).
// Fallbacks byte-preserved: ws>=32KB -> R17 128-block halo kernel +
// finalize; else R8 single-block.

#define NN    4096
#define CHK   32            // R17 fallback: chunk nodes
#define EXT   48            // R17 fallback: chunk + 2*8 halo
#define PEXT  40            // R17 fallback: chunk + 2*4 halo
#define NGRID 128           // R17 fallback grid
#define WS_R17 (NGRID * 64u * 4u)

#define NBLK2 256           // pipeline grid (16 nodes/block)
#define PEXT2 24            // 16 + 2*4
#define WS_PIPE ((3u * NN * 64u + NBLK2 * 64u) * 4u)

typedef float v4f __attribute__((ext_vector_type(4)));
typedef int   v4i __attribute__((ext_vector_type(4)));

struct Smem {
    float As[EXT][64];
    float Bs[EXT][64];
    float Gs[EXT][64];
    float Hs[16][64];
    float ps[PEXT][8][2];
    float dinvs[PEXT][2];
    float facs[PEXT][2];
    float red[1024];
    float pooled[64];
    float hid[128];
};

struct SmemK2 {
    float As[PEXT2][64];
    float Bs[32][64];
    float Gs[32][64];
    float ps[PEXT2][8][2];
    float dinvs[PEXT2][2];
    float facs[PEXT2][2];
    float red[1024];
};

struct SmemFin {
    float Wc1s[64][128];
    float Wc2s[128][8];
    float red[256];
    float pooled[64];
    float hid[128];
};

template <bool F32>
static __device__ __forceinline__ float ldv(const void* p, int i) {
    if constexpr (F32) return ((const float*)p)[i];
    else return __bfloat162float(((const __hip_bfloat16*)p)[i]);
}

static __device__ __forceinline__ float ldr(const void* p, int i, bool f32) {
    if (f32) return ((const float*)p)[i];
    return __bfloat162float(((const __hip_bfloat16*)p)[i]);
}

static __device__ __forceinline__ float blo(unsigned u) {
    return __uint_as_float(u << 16);
}
static __device__ __forceinline__ float bhi(unsigned u) {
    return __uint_as_float(u & 0xFFFF0000u);
}

// ---------- R8/R17-proven halo body (fallback paths) ----------
template <bool F32>
static __device__ void body(Smem& sm,
    const void* ef, const void* We, const void* be, const void* M1w,
    const void* M1b, const void* M2w, const void* M2b, const void* W1,
    const void* W2, const void* Wc1, const void* bc1, const void* Wc2,
    const void* bc2, void* out)
{
    const int t = threadIdx.x;
    const int c = t & 63;
    const int w = t >> 6;
    const int a = (t >> 6) & 1;
    const int ms = t >> 7;

    const float m1b_c = ldv<F32>(M1b, c);
    const float m2w0  = ldv<F32>(M2w, c * 2 + 0);
    const float m2w1  = ldv<F32>(M2w, c * 2 + 1);
    const float m2b0  = ldv<F32>(M2b, 0);
    const float m2b1  = ldv<F32>(M2b, 1);
    const float cs0 = ldv<F32>(W1, 0) + ldv<F32>(W1, 2);
    const float cs1 = ldv<F32>(W1, 1) + ldv<F32>(W1, 3);
    const float bec = ldv<F32>(be, c);

    float accY = 0.f;

    for (int ch = blockIdx.x; ch < NN / CHK; ch += gridDim.x) {
        const int c0 = ch * CHK;
        for (int pp = 0; pp < EXT / 16; ++pp) {
            const int q  = pp * 16 + w;
            const int gi = (c0 - 8 + q) & (NN - 1);
            float aA = 0.f, aB = 0.f, aH = bec;
            #pragma unroll 2
            for (int k = 0; k < 128; ++k) {
                const float ev = ldv<F32>(ef, gi * 128 + k);
                aA += ev * ldv<F32>(M1w, k * 64 + c);
                aB += ev * ldv<F32>(M1w, 8192 + k * 64 + c);
                aH += ev * ldv<F32>(We, k * 64 + c);
            }
            sm.As[q][c] = aA;
            sm.Bs[q][c] = aB;
            sm.Hs[w][c] = fmaxf(aH, 0.f);
            __syncthreads();
            float aG = 0.f;
            #pragma unroll 2
            for (int k = 0; k < 64; ++k)
                aG += sm.Hs[w][k] * ldv<F32>(W2, k * 64 + c);
            sm.Gs[q][c] = aG;
            __syncthreads();
        }
        for (int pi = w; pi < PEXT * 8; pi += 16) {
            const int r  = pi >> 3;
            const int tt = pi & 7;
            const int off = (tt < 4) ? (tt - 4) : (tt - 3);
            const float h = fmaxf(sm.As[r + 4][c] + sm.Bs[r + 4 + off][c] + m1b_c, 0.f);
            float q0 = h * m2w0, q1 = h * m2w1;
            #pragma unroll
            for (int d2 = 32; d2; d2 >>= 1) {
                q0 += __shfl_xor(q0, d2);
                q1 += __shfl_xor(q1, d2);
            }
            if (c == 0) {
                sm.ps[r][tt][0] = q0 + m2b0;
                sm.ps[r][tt][1] = q1 + m2b1;
            }
        }
        __syncthreads();
        if (t < PEXT * 2) {
            const int r = t >> 1, aa = t & 1;
            float s = 0.f;
            #pragma unroll
            for (int tt = 0; tt < 8; ++tt) { const float p = sm.ps[r][tt][aa]; s += p * p; }
            const float dv = 1.f / sqrtf(fmaxf(s + 1e-5f, 1e-6f));
            sm.dinvs[r][aa] = dv;
            sm.facs[r][aa]  = 1.f - dv * dv * s;
        }
        __syncthreads();
        const float csa = a ? cs1 : cs0;
        #pragma unroll
        for (int it = 0; it < 4; ++it) {
            const int m = it * 8 + ms;
            const int r = m + 4;
            const int g = m + 8;
            const float di = sm.dinvs[r][a];
            float v = sm.facs[r][a] * sm.Gs[g][c];
            #pragma unroll
            for (int tt = 0; tt < 8; ++tt) {
                const int off = (tt < 4) ? (tt - 4) : (tt - 3);
                v += di * sm.ps[r + off][7 - tt][a] * sm.ps[r][tt][a]
                        * sm.dinvs[r + off][a] * sm.Gs[g + off][c];
            }
            const float x = csa * v;
            accY += (x > 0.f) ? x : expm1f(x);
        }
        __syncthreads();
    }

    sm.red[t] = accY;
    __syncthreads();

    if (gridDim.x > 1) {
        if (t < 64) {
            float s = 0.f;
            #pragma unroll
            for (int g2 = 0; g2 < 16; ++g2) s += sm.red[(g2 << 6) + t];
            ((float*)out)[blockIdx.x * 64 + t] = s;
        }
        return;
    }

    if (t < 64) {
        float s = 0.f;
        #pragma unroll
        for (int g2 = 0; g2 < 16; ++g2) s += sm.red[(g2 << 6) + t];
        sm.pooled[t] = s * (1.f / 8192.f);
    }
    __syncthreads();
    if (t < 128) {
        float acc = ldv<F32>(bc1, t);
        #pragma unroll 8
        for (int k = 0; k < 64; ++k) acc += sm.pooled[k] * ldv<F32>(Wc1, k * 128 + t);
        sm.hid[t] = fmaxf(acc, 0.f);
    }
    __syncthreads();
    if (t < 8) {
        float acc = ldv<F32>(bc2, t);
        #pragma unroll 8
        for (int k = 0; k < 128; ++k) acc += sm.hid[k] * ldv<F32>(Wc2, k * 8 + t);
        if constexpr (F32) ((float*)out)[t] = acc;
        else ((__hip_bfloat16*)out)[t] = __float2bfloat16(acc);
    }
}

// ---------- K1: MFMA GEMM ef@[M1wA|M1wB|We] + VALU stage-2 ----------
// grid 256 x 256 thr (4 waves). Wcat rows padded to 194 u16 (97 u32):
// frag reads land groups on banks +8 apart -> conflict-free.
__global__ __launch_bounds__(256) void sheaf_k1(
    const void* ef, const void* We, const void* be, const void* M1w,
    const void* W2, float* A, float* B, float* G)
{
    __shared__ unsigned short Wcat[128][194];   // [k][j] cat weights, 192+2 pad
    __shared__ unsigned short W2T[64][66];      // [c][k] transposed W2
    __shared__ float Hs[16][64];
    __shared__ int flag;
    const int t = threadIdx.x;
    if (t == 0) flag = 0;
    __syncthreads();
    {
        const __hip_bfloat16* efh = (const __hip_bfloat16*)ef;
        bool big = false;
        #pragma unroll
        for (int k = 0; k < 8; ++k) {
            const float v = __bfloat162float(efh[t * 8 + k]);
            big |= !(fabsf(v) < 1e4f);
        }
        if (big) atomicOr(&flag, 1);
    }
    __syncthreads();
    const int nb = blockIdx.x * 16;

    if (!flag) {
        // ---- stage weights (u32 loads, linear LDS) ----
        unsigned* Wc32 = (unsigned*)&Wcat[0][0];        // row k at u32 k*97
        const unsigned* M1u = (const unsigned*)M1w;
        const unsigned* Weu = (const unsigned*)We;
        #pragma unroll
        for (int rep = 0; rep < 16; ++rep) {
            const int s = rep * 256 + t;                // s < 4096
            const int k = s >> 5, jj = s & 31;
            Wc32[k * 97 + jj]      = M1u[s];            // j 0..63  (A cols)
            Wc32[k * 97 + 32 + jj] = M1u[4096 + s];     // j 64..127 (B cols)
            Wc32[k * 97 + 64 + jj] = Weu[s];            // j 128..191 (H cols)
        }
        const unsigned short* W2h = (const unsigned short*)W2;
        #pragma unroll
        for (int rep = 0; rep < 16; ++rep) {
            const int s = rep * 256 + t;                // s < 4096
            W2T[s & 63][s >> 6] = W2h[s];               // transpose
        }
        __syncthreads();

        // ---- MFMA: wave w owns N-tiles 3w..3w+2; M-tile = 16 block nodes ----
        const int l = t & 63, w = t >> 6;
        const int grp = l >> 4, c16 = l & 15;
        const int nt0 = w * 3;
        v4f acc0 = {0.f, 0.f, 0.f, 0.f}, acc1 = acc0, acc2 = acc0;
        const unsigned short* efu = (const unsigned short*)ef;
        #pragma unroll
        for (int ks = 0; ks < 4; ++ks) {
            // A-frag: lane holds ef[nb + (l&15)][ks*32 + (l>>4)*8 + 0..7]
            const v4i av = *(const v4i*)(efu + (nb + c16) * 128 + ks * 32 + grp * 8);
            #pragma unroll
            for (int q = 0; q < 3; ++q) {
                const int nt = nt0 + q;
                // B-frag: lane holds Wcat[ks*32 + (l>>4)*8 + j][nt*16 + (l&15)]
                const unsigned short* src = &Wcat[ks * 32 + grp * 8][nt * 16 + c16];
                v4i bv;
                unsigned short* bu = (unsigned short*)&bv;
                #pragma unroll
                for (int jj = 0; jj < 8; ++jj) bu[jj] = src[jj * 194];
                if (q == 0)
                    asm volatile("v_mfma_f32_16x16x32_bf16 %0, %1, %2, %0"
                                 : "+v"(acc0) : "v"(av), "v"(bv));
                else if (q == 1)
                    asm volatile("v_mfma_f32_16x16x32_bf16 %0, %1, %2, %0"
                                 : "+v"(acc1) : "v"(av), "v"(bv));
                else
                    asm volatile("v_mfma_f32_16x16x32_bf16 %0, %1, %2, %0"
                                 : "+v"(acc2) : "v"(av), "v"(bv));
            }
        }
        asm volatile("s_nop 7\n\ts_nop 7");             // drain MFMA pipe

        // ---- epilogue: C layout col=lane&15, row=(lane>>4)*4+reg ----
        #pragma unroll
        for (int q = 0; q < 3; ++q) {
            const int nt = nt0 + q;
            const v4f accv = (q == 0) ? acc0 : (q == 1) ? acc1 : acc2;
            #pragma unroll
            for (int r = 0; r < 4; ++r) {
                const int node = nb + grp * 4 + r;
                const float v = accv[r];
                if (nt < 4) {
                    A[node * 64 + nt * 16 + c16] = v;
                } else if (nt < 8) {
                    B[node * 64 + (nt - 4) * 16 + c16] = v;
                } else {
                    const float bec = __bfloat162float(
                        ((const __hip_bfloat16*)be)[(nt - 8) * 16 + c16]);
                    Hs[grp * 4 + r][(nt - 8) * 16 + c16] = fmaxf(v + bec, 0.f);
                }
            }
        }
        __syncthreads();

        // ---- stage 2: G = relu(H) @ W2 ; wave w -> nodes 4w..4w+3 ----
        {
            const int c = t & 63;
            const unsigned* W2T32 = (const unsigned*)&W2T[0][0];
            float g0 = 0.f, g1 = 0.f, g2 = 0.f, g3 = 0.f;
            #pragma unroll 4
            for (int kk = 0; kk < 32; ++kk) {
                const unsigned wv = W2T32[c * 33 + kk];  // banks (c+kk)%32: free
                const float w0 = blo(wv), w1 = bhi(wv);
                const float2 h0 = *(const float2*)&Hs[4 * w + 0][2 * kk];
                const float2 h1 = *(const float2*)&Hs[4 * w + 1][2 * kk];
                const float2 h2 = *(const float2*)&Hs[4 * w + 2][2 * kk];
                const float2 h3 = *(const float2*)&Hs[4 * w + 3][2 * kk];
                g0 += h0.x * w0 + h0.y * w1;
                g1 += h1.x * w0 + h1.y * w1;
                g2 += h2.x * w0 + h2.y * w1;
                g3 += h3.x * w0 + h3.y * w1;
            }
            G[(nb + 4 * w + 0) * 64 + c] = g0;
            G[(nb + 4 * w + 1) * 64 + c] = g1;
            G[(nb + 4 * w + 2) * 64 + c] = g2;
            G[(nb + 4 * w + 3) * 64 + c] = g3;
        }
    } else {
        // ---- f32 path (never triggers in practice): direct loops ----
        const float* eff = (const float*)ef;
        const float* M1f = (const float*)M1w;
        const float* Wef = (const float*)We;
        for (int o = t; o < 16 * 192; o += 256) {
            const int n = o / 192, j = o % 192;
            float s = (j >= 128) ? ((const float*)be)[j - 128] : 0.f;
            for (int k = 0; k < 128; ++k) {
                const float e = eff[(nb + n) * 128 + k];
                const float wv = (j < 64) ? M1f[k * 64 + j]
                               : (j < 128) ? M1f[8192 + k * 64 + (j - 64)]
                               : Wef[k * 64 + (j - 128)];
                s += e * wv;
            }
            if (j < 64) A[(nb + n) * 64 + j] = s;
            else if (j < 128) B[(nb + n) * 64 + (j - 64)] = s;
            else Hs[n][j - 128] = fmaxf(s, 0.f);
        }
        __syncthreads();
        const float* W2f = (const float*)W2;
        for (int o = t; o < 16 * 64; o += 256) {
            const int n = o >> 6, c = o & 63;
            float s = 0.f;
            for (int k = 0; k < 64; ++k) s += Hs[n][k] * W2f[k * 64 + c];
            G[(nb + n) * 64 + c] = s;
        }
    }
}

// ---------- K2: sheaf stencil phases 2-4 (R24-proven) ----------
template <bool F32>
static __device__ void k2body(SmemK2& sm,
    const void* M1b, const void* M2w, const void* M2b, const void* W1,
    const float* A, const float* B, const float* G, float* partials)
{
    const int t = threadIdx.x, c = t & 63, w = t >> 6;
    const int base = blockIdx.x * 16;

    for (int idx = t; idx < PEXT2 * 64; idx += 1024) {
        const int r = idx >> 6, cc = idx & 63;
        sm.As[r][cc] = A[(((base - 4 + r) & (NN - 1)) << 6) + cc];
    }
    for (int idx = t; idx < 32 * 64; idx += 1024) {
        const int r = idx >> 6, cc = idx & 63;
        const int gi = ((base - 8 + r) & (NN - 1)) << 6;
        sm.Bs[r][cc] = B[gi + cc];
        sm.Gs[r][cc] = G[gi + cc];
    }
    __syncthreads();

    const float m1b_c = ldv<F32>(M1b, c);
    const float m2w0  = ldv<F32>(M2w, c * 2 + 0);
    const float m2w1  = ldv<F32>(M2w, c * 2 + 1);
    const float m2b0  = ldv<F32>(M2b, 0);
    const float m2b1  = ldv<F32>(M2b, 1);
    const float cs0 = ldv<F32>(W1, 0) + ldv<F32>(W1, 2);
    const float cs1 = ldv<F32>(W1, 1) + ldv<F32>(W1, 3);

    for (int pi = w; pi < PEXT2 * 8; pi += 16) {
        const int r  = pi >> 3;
        const int tt = pi & 7;
        const int off = (tt < 4) ? (tt - 4) : (tt - 3);
        const float h = fmaxf(sm.As[r][c] + sm.Bs[r + 4 + off][c] + m1b_c, 0.f);
        float q0 = h * m2w0, q1 = h * m2w1;
        #pragma unroll
        for (int d2 = 32; d2; d2 >>= 1) {
            q0 += __shfl_xor(q0, d2);
            q1 += __shfl_xor(q1, d2);
        }
        if (c == 0) {
            sm.ps[r][tt][0] = q0 + m2b0;
            sm.ps[r][tt][1] = q1 + m2b1;
        }
    }
    __syncthreads();

    if (t < PEXT2 * 2) {
        const int r = t >> 1, aa = t & 1;
        float s = 0.f;
        #pragma unroll
        for (int tt = 0; tt < 8; ++tt) { const float p = sm.ps[r][tt][aa]; s += p * p; }
        const float dv = 1.f / sqrtf(fmaxf(s + 1e-5f, 1e-6f));
        sm.dinvs[r][aa] = dv;
        sm.facs[r][aa]  = 1.f - dv * dv * s;
    }
    __syncthreads();

    float accY = 0.f;
    #pragma unroll
    for (int it = 0; it < 2; ++it) {
        const int m = it * 8 + (t >> 7);
        const int a = (t >> 6) & 1;
        const int r = m + 4;
        const int g = m + 8;
        const float csa = a ? cs1 : cs0;
        const float di = sm.dinvs[r][a];
        float v = sm.facs[r][a] * sm.Gs[g][c];
        #pragma unroll
        for (int tt = 0; tt < 8; ++tt) {
            const int off = (tt < 4) ? (tt - 4) : (tt - 3);
            v += di * sm.ps[r + off][7 - tt][a] * sm.ps[r][tt][a]
                    * sm.dinvs[r + off][a] * sm.Gs[g + off][c];
        }
        const float x = csa * v;
        accY += (x > 0.f) ? x : expm1f(x);
    }

    sm.red[t] = accY;
    __syncthreads();
    if (t < 64) {
        float s = 0.f;
        #pragma unroll
        for (int g2 = 0; g2 < 16; ++g2) s += sm.red[(g2 << 6) + t];
        partials[blockIdx.x * 64 + t] = s;
    }
}

__global__ __launch_bounds__(1024) void sheaf_k2(
    const void* ef, const void* M1b, const void* M2w, const void* M2b,
    const void* W1, const float* A, const float* B, const float* G,
    float* partials)
{
    __shared__ SmemK2 sm;
    __shared__ int flag;
    const int t = threadIdx.x;
    if (t == 0) flag = 0;
    __syncthreads();
    {
        const __hip_bfloat16* efh = (const __hip_bfloat16*)ef;
        bool big = false;
        #pragma unroll
        for (int k = 0; k < 8; ++k) {
            const float v = __bfloat162float(efh[t * 8 + k]);
            big |= !(fabsf(v) < 1e4f);
        }
        if (big) atomicOr(&flag, 1);
    }
    __syncthreads();
    if (flag) k2body<true >(sm, M1b, M2w, M2b, W1, A, B, G, partials);
    else      k2body<false>(sm, M1b, M2w, M2b, W1, A, B, G, partials);
}

// ---------- finalize: Wc1/Wc2 LDS-staged reduce + classifier ----------
template <bool F32>
static __device__ void finbody(SmemFin& sm,
    const void* Wc1, const void* bc1, const void* Wc2, const void* bc2,
    const float* partials, int nparts, void* out)
{
    const int t = threadIdx.x;

    if constexpr (F32) {
        for (int idx = t; idx < 64 * 128; idx += 256)
            sm.Wc1s[idx >> 7][idx & 127] = ((const float*)Wc1)[idx];
        for (int idx = t; idx < 128 * 8; idx += 256)
            sm.Wc2s[idx >> 3][idx & 7] = ((const float*)Wc2)[idx];
    } else {
        for (int j = t; j < 4096; j += 256) {
            const int k = j >> 6, c2 = (j & 63) * 2;
            const unsigned u = ((const unsigned*)Wc1)[j];
            sm.Wc1s[k][c2] = blo(u);  sm.Wc1s[k][c2 + 1] = bhi(u);
        }
        for (int j = t; j < 512; j += 256) {
            const int k = j >> 2, c2 = (j & 3) * 2;
            const unsigned u = ((const unsigned*)Wc2)[j];
            sm.Wc2s[k][c2] = blo(u);  sm.Wc2s[k][c2 + 1] = bhi(u);
        }
    }

    const int h = t & 63, g = t >> 6;
    float s = 0.f;
    for (int b = g; b < nparts; b += 4) s += partials[b * 64 + h];
    sm.red[t] = s;
    __syncthreads();
    if (t < 64)
        sm.pooled[t] = (sm.red[t] + sm.red[t + 64] + sm.red[t + 128] + sm.red[t + 192])
                       * (1.f / 8192.f);
    __syncthreads();
    if (t < 128) {
        float acc = ldv<F32>(bc1, t);
        #pragma unroll 8
        for (int k = 0; k < 64; ++k) acc = fmaf(sm.pooled[k], sm.Wc1s[k][t], acc);
        sm.hid[t] = fmaxf(acc, 0.f);
    }
    __syncthreads();
    if (t < 8) {
        float acc = ldv<F32>(bc2, t);
        #pragma unroll 8
        for (int k = 0; k < 128; ++k) acc = fmaf(sm.hid[k], sm.Wc2s[k][t], acc);
        if constexpr (F32) ((float*)out)[t] = acc;
        else ((__hip_bfloat16*)out)[t] = __float2bfloat16(acc);
    }
}

__global__ __launch_bounds__(256) void sheaf_finalize(
    const void* ef, const void* Wc1, const void* bc1, const void* Wc2,
    const void* bc2, const float* partials, int nparts, void* out)
{
    __shared__ SmemFin sm;
    __shared__ int flag;
    const int t = threadIdx.x;
    if (t == 0) flag = 0;
    __syncthreads();
    {
        const __hip_bfloat16* efh = (const __hip_bfloat16*)ef;
        bool big = false;
        #pragma unroll
        for (int k = 0; k < 8; ++k) {
            const float v = __bfloat162float(efh[t * 8 + k]);
            big |= !(fabsf(v) < 1e4f);
        }
        if (big) atomicOr(&flag, 1);
    }
    __syncthreads();
    if (flag) finbody<true >(sm, Wc1, bc1, Wc2, bc2, partials, nparts, out);
    else      finbody<false>(sm, Wc1, bc1, Wc2, bc2, partials, nparts, out);
}

__global__ __launch_bounds__(1024) void SheafConvolutionalNetwork_81698867905240_kernel(
    const void* ef, const void* We, const void* be, const void* M1w,
    const void* M1b, const void* M2w, const void* M2b, const void* W1,
    const void* W2, const void* Wc1, const void* bc1, const void* Wc2,
    const void* bc2, void* out)
{
    __shared__ Smem sm;
    __shared__ int flag;
    const int t = threadIdx.x;
    if (t == 0) flag = 0;
    __syncthreads();
    {
        const __hip_bfloat16* efh = (const __hip_bfloat16*)ef;
        bool big = false;
        #pragma unroll
        for (int k = 0; k < 8; ++k) {
            const float v = __bfloat162float(efh[t * 8 + k]);
            big |= !(fabsf(v) < 1e4f);
        }
        if (big) atomicOr(&flag, 1);
    }
    __syncthreads();
    if (flag)
        body<true >(sm, ef, We, be, M1w, M1b, M2w, M2b, W1, W2, Wc1, bc1, Wc2, bc2, out);
    else
        body<false>(sm, ef, We, be, M1w, M1b, M2w, M2b, W1, W2, Wc1, bc1, Wc2, bc2, out);
}

extern "C" void kernel_launch(void* const* d_in, const int* in_sizes, int n_in,
                              void* d_out, int out_size, void* d_ws, size_t ws_size,
                              hipStream_t stream)
{
    (void)in_sizes; (void)n_in; (void)out_size;
    (void)hipGetLastError();   // clear stale error

    if (d_ws != nullptr && ws_size >= (size_t)WS_PIPE) {
        float* A = (float*)d_ws;
        float* B = A + NN * 64;
        float* G = B + NN * 64;
        float* partials = G + NN * 64;
        sheaf_k1<<<dim3(NBLK2), dim3(256), 0, stream>>>(
            d_in[0], d_in[1], d_in[2], d_in[3], d_in[8], A, B, G);
        sheaf_k2<<<dim3(NBLK2), dim3(1024), 0, stream>>>(
            d_in[0], d_in[4], d_in[5], d_in[6], d_in[7], A, B, G, partials);
        sheaf_finalize<<<dim3(1), dim3(256), 0, stream>>>(
            d_in[0], d_in[9], d_in[10], d_in[11], d_in[12],
            partials, NBLK2, d_out);
    } else if (d_ws != nullptr && ws_size >= (size_t)WS_R17) {
        SheafConvolutionalNetwork_81698867905240_kernel<<<dim3(NGRID), dim3(1024), 0, stream>>>(
            d_in[0], d_in[1], d_in[2], d_in[3], d_in[4], d_in[5], d_in[6],
            d_in[7], d_in[8], d_in[9], d_in[10], d_in[11], d_in[12], d_ws);
        sheaf_finalize<<<dim3(1), dim3(256), 0, stream>>>(
            d_in[0], d_in[9], d_in[10], d_in[11], d_in[12],
            (const float*)d_ws, NGRID, d_out);
    } else {
        SheafConvolutionalNetwork_81698867905240_kernel<<<dim3(1), dim3(1024), 0, stream>>>(
            d_in[0], d_in[1], d_in[2], d_in[3], d_in[4], d_in[5], d_in[6],
            d_in[7], d_in[8], d_in[9], d_in[10], d_in[11], d_in[12], d_out);
    }

    if (hipGetLastError() != hipSuccess)
        (void)hipMemsetAsync(d_out, 0x41, 16, stream);
}

// Round 27
// 76.159 us; speedup vs baseline: 1.8636x; 1.8636x over previous
//
#include <hip/hip_runtime.h>
#include <hip/hip_bf16.h>

// Sheaf CNN on the fixed ring graph (offsets ±1..4 mod 4096, degree 8).
// 3-dispatch pipeline (R24 base), packed-weights K1:
//   K1 (1024 thr): M1w lo|hi packed per-u32 in LDS (P1), We/W2 as u16;
//       per-wave GEMV reads 2 LDS words + 1 broadcast per k (was 3+1);
//       LDS 68KB -> 2 blocks/CU. A,B,G -> d_ws.
//   K2: phases 2-4 per 16-node chunk (R24-proven, byte-identical)
//   K3: finalize with Wc1/Wc2 LDS-staged (R24-proven, byte-identical)
// MFMA-K1 closed (R26: 4 waves/CU latency-bound, 128us). Fused closed
// (R21/R25: 105us). Fallbacks byte-preserved: ws>=32KB -> R17 128-block
// halo kernel + finalize; else R8 single-block.

#define NN    4096
#define CHK   32            // R17 fallback: chunk nodes
#define EXT   48            // R17 fallback: chunk + 2*8 halo
#define PEXT  40            // R17 fallback: chunk + 2*4 halo
#define NGRID 128           // R17 fallback grid
#define WS_R17 (NGRID * 64u * 4u)

#define NBLK2 256           // pipeline grid (16 nodes/block)
#define PEXT2 24            // 16 + 2*4
#define WS_PIPE ((3u * NN * 64u + NBLK2 * 64u) * 4u)

struct Smem {
    float As[EXT][64];
    float Bs[EXT][64];
    float Gs[EXT][64];
    float Hs[16][64];
    float ps[PEXT][8][2];
    float dinvs[PEXT][2];
    float facs[PEXT][2];
    float red[1024];
    float pooled[64];
    float hid[128];
};

struct SmemK1 {
    unsigned        P1[128][64];    // Wa|Wb packed   (32KB)
    unsigned short  Wh16[128][64];  // We             (16KB)
    unsigned short  W216[64][64];   // W2             (8KB)
    float           efs[16][128];   // ef rows        (8KB)
    float           Hs[16][64];     // relu(ef@We+be) (4KB)
};

struct SmemK2 {
    float As[PEXT2][64];
    float Bs[32][64];
    float Gs[32][64];
    float ps[PEXT2][8][2];
    float dinvs[PEXT2][2];
    float facs[PEXT2][2];
    float red[1024];
};

struct SmemFin {
    float Wc1s[64][128];
    float Wc2s[128][8];
    float red[256];
    float pooled[64];
    float hid[128];
};

template <bool F32>
static __device__ __forceinline__ float ldv(const void* p, int i) {
    if constexpr (F32) return ((const float*)p)[i];
    else return __bfloat162float(((const __hip_bfloat16*)p)[i]);
}

static __device__ __forceinline__ float ldr(const void* p, int i, bool f32) {
    if (f32) return ((const float*)p)[i];
    return __bfloat162float(((const __hip_bfloat16*)p)[i]);
}

static __device__ __forceinline__ float blo(unsigned u) {
    return __uint_as_float(u << 16);
}
static __device__ __forceinline__ float bhi(unsigned u) {
    return __uint_as_float(u & 0xFFFF0000u);
}
static __device__ __forceinline__ float b16f(unsigned short u) {
    return __uint_as_float(((unsigned)u) << 16);
}

// ---------- R8/R17-proven halo body (fallback paths) ----------
template <bool F32>
static __device__ void body(Smem& sm,
    const void* ef, const void* We, const void* be, const void* M1w,
    const void* M1b, const void* M2w, const void* M2b, const void* W1,
    const void* W2, const void* Wc1, const void* bc1, const void* Wc2,
    const void* bc2, void* out)
{
    const int t = threadIdx.x;
    const int c = t & 63;
    const int w = t >> 6;
    const int a = (t >> 6) & 1;
    const int ms = t >> 7;

    const float m1b_c = ldv<F32>(M1b, c);
    const float m2w0  = ldv<F32>(M2w, c * 2 + 0);
    const float m2w1  = ldv<F32>(M2w, c * 2 + 1);
    const float m2b0  = ldv<F32>(M2b, 0);
    const float m2b1  = ldv<F32>(M2b, 1);
    const float cs0 = ldv<F32>(W1, 0) + ldv<F32>(W1, 2);
    const float cs1 = ldv<F32>(W1, 1) + ldv<F32>(W1, 3);
    const float bec = ldv<F32>(be, c);

    float accY = 0.f;

    for (int ch = blockIdx.x; ch < NN / CHK; ch += gridDim.x) {
        const int c0 = ch * CHK;
        for (int pp = 0; pp < EXT / 16; ++pp) {
            const int q  = pp * 16 + w;
            const int gi = (c0 - 8 + q) & (NN - 1);
            float aA = 0.f, aB = 0.f, aH = bec;
            #pragma unroll 2
            for (int k = 0; k < 128; ++k) {
                const float ev = ldv<F32>(ef, gi * 128 + k);
                aA += ev * ldv<F32>(M1w, k * 64 + c);
                aB += ev * ldv<F32>(M1w, 8192 + k * 64 + c);
                aH += ev * ldv<F32>(We, k * 64 + c);
            }
            sm.As[q][c] = aA;
            sm.Bs[q][c] = aB;
            sm.Hs[w][c] = fmaxf(aH, 0.f);
            __syncthreads();
            float aG = 0.f;
            #pragma unroll 2
            for (int k = 0; k < 64; ++k)
                aG += sm.Hs[w][k] * ldv<F32>(W2, k * 64 + c);
            sm.Gs[q][c] = aG;
            __syncthreads();
        }
        for (int pi = w; pi < PEXT * 8; pi += 16) {
            const int r  = pi >> 3;
            const int tt = pi & 7;
            const int off = (tt < 4) ? (tt - 4) : (tt - 3);
            const float h = fmaxf(sm.As[r + 4][c] + sm.Bs[r + 4 + off][c] + m1b_c, 0.f);
            float q0 = h * m2w0, q1 = h * m2w1;
            #pragma unroll
            for (int d2 = 32; d2; d2 >>= 1) {
                q0 += __shfl_xor(q0, d2);
                q1 += __shfl_xor(q1, d2);
            }
            if (c == 0) {
                sm.ps[r][tt][0] = q0 + m2b0;
                sm.ps[r][tt][1] = q1 + m2b1;
            }
        }
        __syncthreads();
        if (t < PEXT * 2) {
            const int r = t >> 1, aa = t & 1;
            float s = 0.f;
            #pragma unroll
            for (int tt = 0; tt < 8; ++tt) { const float p = sm.ps[r][tt][aa]; s += p * p; }
            const float dv = 1.f / sqrtf(fmaxf(s + 1e-5f, 1e-6f));
            sm.dinvs[r][aa] = dv;
            sm.facs[r][aa]  = 1.f - dv * dv * s;
        }
        __syncthreads();
        const float csa = a ? cs1 : cs0;
        #pragma unroll
        for (int it = 0; it < 4; ++it) {
            const int m = it * 8 + ms;
            const int r = m + 4;
            const int g = m + 8;
            const float di = sm.dinvs[r][a];
            float v = sm.facs[r][a] * sm.Gs[g][c];
            #pragma unroll
            for (int tt = 0; tt < 8; ++tt) {
                const int off = (tt < 4) ? (tt - 4) : (tt - 3);
                v += di * sm.ps[r + off][7 - tt][a] * sm.ps[r][tt][a]
                        * sm.dinvs[r + off][a] * sm.Gs[g + off][c];
            }
            const float x = csa * v;
            accY += (x > 0.f) ? x : expm1f(x);
        }
        __syncthreads();
    }

    sm.red[t] = accY;
    __syncthreads();

    if (gridDim.x > 1) {
        if (t < 64) {
            float s = 0.f;
            #pragma unroll
            for (int g2 = 0; g2 < 16; ++g2) s += sm.red[(g2 << 6) + t];
            ((float*)out)[blockIdx.x * 64 + t] = s;
        }
        return;
    }

    if (t < 64) {
        float s = 0.f;
        #pragma unroll
        for (int g2 = 0; g2 < 16; ++g2) s += sm.red[(g2 << 6) + t];
        sm.pooled[t] = s * (1.f / 8192.f);
    }
    __syncthreads();
    if (t < 128) {
        float acc = ldv<F32>(bc1, t);
        #pragma unroll 8
        for (int k = 0; k < 64; ++k) acc += sm.pooled[k] * ldv<F32>(Wc1, k * 128 + t);
        sm.hid[t] = fmaxf(acc, 0.f);
    }
    __syncthreads();
    if (t < 8) {
        float acc = ldv<F32>(bc2, t);
        #pragma unroll 8
        for (int k = 0; k < 128; ++k) acc += sm.hid[k] * ldv<F32>(Wc2, k * 8 + t);
        if constexpr (F32) ((float*)out)[t] = acc;
        else ((__hip_bfloat16*)out)[t] = __float2bfloat16(acc);
    }
}

// ---------- K1: node GEMVs, packed bf16 weights in LDS ----------
__global__ __launch_bounds__(1024) void sheaf_k1(
    const void* ef, const void* We, const void* be, const void* M1w,
    const void* W2, float* A, float* B, float* G)
{
    __shared__ SmemK1 sm;
    __shared__ int flag;
    const int t = threadIdx.x, c = t & 63, w = t >> 6;
    const int base = blockIdx.x * 16;
    if (t == 0) flag = 0;
    __syncthreads();
    {
        const __hip_bfloat16* efh = (const __hip_bfloat16*)ef;
        bool big = false;
        #pragma unroll
        for (int k = 0; k < 8; ++k) {
            const float v = __bfloat162float(efh[t * 8 + k]);
            big |= !(fabsf(v) < 1e4f);
        }
        if (big) atomicOr(&flag, 1);
    }
    __syncthreads();

    if (!flag) {
        // ---- stage: pack M1w lo|hi, raw-copy We/W2, expand ef ----
        const unsigned* M1u = (const unsigned*)M1w;
        const unsigned* Weu = (const unsigned*)We;
        const unsigned* W2u = (const unsigned*)W2;
        const unsigned* efu = (const unsigned*)ef;
        #pragma unroll
        for (int rep = 0; rep < 4; ++rep) {
            const int j = rep * 1024 + t;               // j < 4096
            const unsigned a = M1u[j];                  // Wa pair
            const unsigned b = M1u[4096 + j];           // Wb pair
            const int k = j >> 5, c2 = (j & 31) * 2;
            sm.P1[k][c2]     = (a & 0xFFFFu) | (b << 16);
            sm.P1[k][c2 + 1] = (a >> 16) | (b & 0xFFFF0000u);
            ((unsigned*)sm.Wh16)[j] = Weu[j];
        }
        #pragma unroll
        for (int rep = 0; rep < 2; ++rep)
            ((unsigned*)sm.W216)[rep * 1024 + t] = W2u[rep * 1024 + t];
        {
            const int j = t;                            // 16*64 = 1024 words
            const int n = j >> 6, kk = (j & 63) * 2;
            const unsigned u = efu[(base << 6) + j];
            sm.efs[n][kk]     = blo(u);
            sm.efs[n][kk + 1] = bhi(u);
        }
        __syncthreads();

        // ---- GEMV: wave w owns node base+w; 2 LDS words + 1 bcast per k ----
        const int n = w;
        float aA = 0.f, aB = 0.f, aH = ldv<false>(be, c);
        #pragma unroll 8
        for (int k = 0; k < 128; ++k) {
            const float e = sm.efs[n][k];               // broadcast (free)
            const unsigned p = sm.P1[k][c];             // 2-way bank (free)
            aA = fmaf(e, blo(p), aA);
            aB = fmaf(e, bhi(p), aB);
            aH = fmaf(e, b16f(sm.Wh16[k][c]), aH);
        }
        A[((base + n) << 6) + c] = aA;
        B[((base + n) << 6) + c] = aB;
        sm.Hs[n][c] = fmaxf(aH, 0.f);
        __syncthreads();

        float aG = 0.f;
        #pragma unroll 8
        for (int k = 0; k < 64; ++k)
            aG = fmaf(sm.Hs[n][k], b16f(sm.W216[k][c]), aG);
        G[((base + n) << 6) + c] = aG;
    } else {
        // ---- f32 path (never triggers in practice): direct loops ----
        const float* eff = (const float*)ef;
        const float* M1f = (const float*)M1w;
        const float* Wef = (const float*)We;
        for (int o = t; o < 16 * 192; o += 1024) {
            const int n = o / 192, j = o % 192;
            float s = (j >= 128) ? ((const float*)be)[j - 128] : 0.f;
            for (int k = 0; k < 128; ++k) {
                const float e = eff[(base + n) * 128 + k];
                const float wv = (j < 64) ? M1f[k * 64 + j]
                               : (j < 128) ? M1f[8192 + k * 64 + (j - 64)]
                               : Wef[k * 64 + (j - 128)];
                s += e * wv;
            }
            if (j < 64) A[(base + n) * 64 + j] = s;
            else if (j < 128) B[(base + n) * 64 + (j - 64)] = s;
            else sm.Hs[n][j - 128] = fmaxf(s, 0.f);
        }
        __syncthreads();
        const float* W2f = (const float*)W2;
        for (int o = t; o < 16 * 64; o += 1024) {
            const int n = o >> 6, cc = o & 63;
            float s = 0.f;
            for (int k = 0; k < 64; ++k) s += sm.Hs[n][k] * W2f[k * 64 + cc];
            G[(base + n) * 64 + cc] = s;
        }
    }
}

// ---------- K2: sheaf stencil phases 2-4 (R24-proven) ----------
template <bool F32>
static __device__ void k2body(SmemK2& sm,
    const void* M1b, const void* M2w, const void* M2b, const void* W1,
    const float* A, const float* B, const float* G, float* partials)
{
    const int t = threadIdx.x, c = t & 63, w = t >> 6;
    const int base = blockIdx.x * 16;

    for (int idx = t; idx < PEXT2 * 64; idx += 1024) {
        const int r = idx >> 6, cc = idx & 63;
        sm.As[r][cc] = A[(((base - 4 + r) & (NN - 1)) << 6) + cc];
    }
    for (int idx = t; idx < 32 * 64; idx += 1024) {
        const int r = idx >> 6, cc = idx & 63;
        const int gi = ((base - 8 + r) & (NN - 1)) << 6;
        sm.Bs[r][cc] = B[gi + cc];
        sm.Gs[r][cc] = G[gi + cc];
    }
    __syncthreads();

    const float m1b_c = ldv<F32>(M1b, c);
    const float m2w0  = ldv<F32>(M2w, c * 2 + 0);
    const float m2w1  = ldv<F32>(M2w, c * 2 + 1);
    const float m2b0  = ldv<F32>(M2b, 0);
    const float m2b1  = ldv<F32>(M2b, 1);
    const float cs0 = ldv<F32>(W1, 0) + ldv<F32>(W1, 2);
    const float cs1 = ldv<F32>(W1, 1) + ldv<F32>(W1, 3);

    for (int pi = w; pi < PEXT2 * 8; pi += 16) {
        const int r  = pi >> 3;
        const int tt = pi & 7;
        const int off = (tt < 4) ? (tt - 4) : (tt - 3);
        const float h = fmaxf(sm.As[r][c] + sm.Bs[r + 4 + off][c] + m1b_c, 0.f);
        float q0 = h * m2w0, q1 = h * m2w1;
        #pragma unroll
        for (int d2 = 32; d2; d2 >>= 1) {
            q0 += __shfl_xor(q0, d2);
            q1 += __shfl_xor(q1, d2);
        }
        if (c == 0) {
            sm.ps[r][tt][0] = q0 + m2b0;
            sm.ps[r][tt][1] = q1 + m2b1;
        }
    }
    __syncthreads();

    if (t < PEXT2 * 2) {
        const int r = t >> 1, aa = t & 1;
        float s = 0.f;
        #pragma unroll
        for (int tt = 0; tt < 8; ++tt) { const float p = sm.ps[r][tt][aa]; s += p * p; }
        const float dv = 1.f / sqrtf(fmaxf(s + 1e-5f, 1e-6f));
        sm.dinvs[r][aa] = dv;
        sm.facs[r][aa]  = 1.f - dv * dv * s;
    }
    __syncthreads();

    float accY = 0.f;
    #pragma unroll
    for (int it = 0; it < 2; ++it) {
        const int m = it * 8 + (t >> 7);
        const int a = (t >> 6) & 1;
        const int r = m + 4;
        const int g = m + 8;
        const float csa = a ? cs1 : cs0;
        const float di = sm.dinvs[r][a];
        float v = sm.facs[r][a] * sm.Gs[g][c];
        #pragma unroll
        for (int tt = 0; tt < 8; ++tt) {
            const int off = (tt < 4) ? (tt - 4) : (tt - 3);
            v += di * sm.ps[r + off][7 - tt][a] * sm.ps[r][tt][a]
                    * sm.dinvs[r + off][a] * sm.Gs[g + off][c];
        }
        const float x = csa * v;
        accY += (x > 0.f) ? x : expm1f(x);
    }

    sm.red[t] = accY;
    __syncthreads();
    if (t < 64) {
        float s = 0.f;
        #pragma unroll
        for (int g2 = 0; g2 < 16; ++g2) s += sm.red[(g2 << 6) + t];
        partials[blockIdx.x * 64 + t] = s;
    }
}

__global__ __launch_bounds__(1024) void sheaf_k2(
    const void* ef, const void* M1b, const void* M2w, const void* M2b,
    const void* W1, const float* A, const float* B, const float* G,
    float* partials)
{
    __shared__ SmemK2 sm;
    __shared__ int flag;
    const int t = threadIdx.x;
    if (t == 0) flag = 0;
    __syncthreads();
    {
        const __hip_bfloat16* efh = (const __hip_bfloat16*)ef;
        bool big = false;
        #pragma unroll
        for (int k = 0; k < 8; ++k) {
            const float v = __bfloat162float(efh[t * 8 + k]);
            big |= !(fabsf(v) < 1e4f);
        }
        if (big) atomicOr(&flag, 1);
    }
    __syncthreads();
    if (flag) k2body<true >(sm, M1b, M2w, M2b, W1, A, B, G, partials);
    else      k2body<false>(sm, M1b, M2w, M2b, W1, A, B, G, partials);
}

// ---------- finalize: Wc1/Wc2 LDS-staged reduce + classifier ----------
template <bool F32>
static __device__ void finbody(SmemFin& sm,
    const void* Wc1, const void* bc1, const void* Wc2, const void* bc2,
    const float* partials, int nparts, void* out)
{
    const int t = threadIdx.x;

    if constexpr (F32) {
        for (int idx = t; idx < 64 * 128; idx += 256)
            sm.Wc1s[idx >> 7][idx & 127] = ((const float*)Wc1)[idx];
        for (int idx = t; idx < 128 * 8; idx += 256)
            sm.Wc2s[idx >> 3][idx & 7] = ((const float*)Wc2)[idx];
    } else {
        for (int j = t; j < 4096; j += 256) {
            const int k = j >> 6, c2 = (j & 63) * 2;
            const unsigned u = ((const unsigned*)Wc1)[j];
            sm.Wc1s[k][c2] = blo(u);  sm.Wc1s[k][c2 + 1] = bhi(u);
        }
        for (int j = t; j < 512; j += 256) {
            const int k = j >> 2, c2 = (j & 3) * 2;
            const unsigned u = ((const unsigned*)Wc2)[j];
            sm.Wc2s[k][c2] = blo(u);  sm.Wc2s[k][c2 + 1] = bhi(u);
        }
    }

    const int h = t & 63, g = t >> 6;
    float s = 0.f;
    for (int b = g; b < nparts; b += 4) s += partials[b * 64 + h];
    sm.red[t] = s;
    __syncthreads();
    if (t < 64)
        sm.pooled[t] = (sm.red[t] + sm.red[t + 64] + sm.red[t + 128] + sm.red[t + 192])
                       * (1.f / 8192.f);
    __syncthreads();
    if (t < 128) {
        float acc = ldv<F32>(bc1, t);
        #pragma unroll 8
        for (int k = 0; k < 64; ++k) acc = fmaf(sm.pooled[k], sm.Wc1s[k][t], acc);
        sm.hid[t] = fmaxf(acc, 0.f);
    }
    __syncthreads();
    if (t < 8) {
        float acc = ldv<F32>(bc2, t);
        #pragma unroll 8
        for (int k = 0; k < 128; ++k) acc = fmaf(sm.hid[k], sm.Wc2s[k][t], acc);
        if constexpr (F32) ((float*)out)[t] = acc;
        else ((__hip_bfloat16*)out)[t] = __float2bfloat16(acc);
    }
}

__global__ __launch_bounds__(256) void sheaf_finalize(
    const void* ef, const void* Wc1, const void* bc1, const void* Wc2,
    const void* bc2, const float* partials, int nparts, void* out)
{
    __shared__ SmemFin sm;
    __shared__ int flag;
    const int t = threadIdx.x;
    if (t == 0) flag = 0;
    __syncthreads();
    {
        const __hip_bfloat16* efh = (const __hip_bfloat16*)ef;
        bool big = false;
        #pragma unroll
        for (int k = 0; k < 8; ++k) {
            const float v = __bfloat162float(efh[t * 8 + k]);
            big |= !(fabsf(v) < 1e4f);
        }
        if (big) atomicOr(&flag, 1);
    }
    __syncthreads();
    if (flag) finbody<true >(sm, Wc1, bc1, Wc2, bc2, partials, nparts, out);
    else      finbody<false>(sm, Wc1, bc1, Wc2, bc2, partials, nparts, out);
}

__global__ __launch_bounds__(1024) void SheafConvolutionalNetwork_81698867905240_kernel(
    const void* ef, const void* We, const void* be, const void* M1w,
    const void* M1b, const void* M2w, const void* M2b, const void* W1,
    const void* W2, const void* Wc1, const void* bc1, const void* Wc2,
    const void* bc2, void* out)
{
    __shared__ Smem sm;
    __shared__ int flag;
    const int t = threadIdx.x;
    if (t == 0) flag = 0;
    __syncthreads();
    {
        const __hip_bfloat16* efh = (const __hip_bfloat16*)ef;
        bool big = false;
        #pragma unroll
        for (int k = 0; k < 8; ++k) {
            const float v = __bfloat162float(efh[t * 8 + k]);
            big |= !(fabsf(v) < 1e4f);
        }
        if (big) atomicOr(&flag, 1);
    }
    __syncthreads();
    if (flag)
        body<true >(sm, ef, We, be, M1w, M1b, M2w, M2b, W1, W2, Wc1, bc1, Wc2, bc2, out);
    else
        body<false>(sm, ef, We, be, M1w, M1b, M2w, M2b, W1, W2, Wc1, bc1, Wc2, bc2, out);
}

extern "C" void kernel_launch(void* const* d_in, const int* in_sizes, int n_in,
                              void* d_out, int out_size, void* d_ws, size_t ws_size,
                              hipStream_t stream)
{
    (void)in_sizes; (void)n_in; (void)out_size;
    (void)hipGetLastError();   // clear stale error

    if (d_ws != nullptr && ws_size >= (size_t)WS_PIPE) {
        float* A = (float*)d_ws;
        float* B = A + NN * 64;
        float* G = B + NN * 64;
        float* partials = G + NN * 64;
        sheaf_k1<<<dim3(NBLK2), dim3(1024), 0, stream>>>(
            d_in[0], d_in[1], d_in[2], d_in[3], d_in[8], A, B, G);
        sheaf_k2<<<dim3(NBLK2), dim3(1024), 0, stream>>>(
            d_in[0], d_in[4], d_in[5], d_in[6], d_in[7], A, B, G, partials);
        sheaf_finalize<<<dim3(1), dim3(256), 0, stream>>>(
            d_in[0], d_in[9], d_in[10], d_in[11], d_in[12],
            partials, NBLK2, d_out);
    } else if (d_ws != nullptr && ws_size >= (size_t)WS_R17) {
        SheafConvolutionalNetwork_81698867905240_kernel<<<dim3(NGRID), dim3(1024), 0, stream>>>(
            d_in[0], d_in[1], d_in[2], d_in[3], d_in[4], d_in[5], d_in[6],
            d_in[7], d_in[8], d_in[9], d_in[10], d_in[11], d_in[12], d_ws);
        sheaf_finalize<<<dim3(1), dim3(256), 0, stream>>>(
            d_in[0], d_in[9], d_in[10], d_in[11], d_in[12],
            (const float*)d_ws, NGRID, d_out);
    } else {
        SheafConvolutionalNetwork_81698867905240_kernel<<<dim3(1), dim3(1024), 0, stream>>>(
            d_in[0], d_in[1], d_in[2], d_in[3], d_in[4], d_in[5], d_in[6],
            d_in[7], d_in[8], d_in[9], d_in[10], d_in[11], d_in[12], d_out);
    }

    if (hipGetLastError() != hipSuccess)
        (void)hipMemsetAsync(d_out, 0x41, 16, stream);
}

// Round 28
// 75.721 us; speedup vs baseline: 1.8743x; 1.0058x over previous
//
#include <hip/hip_runtime.h>
#include <hip/hip_bf16.h>

// Sheaf CNN on the fixed ring graph (offsets ±1..4 mod 4096, degree 8).
// 3-dispatch pipeline (R24 base), quad-broadcast K1:
//   K1 (1024 thr): weights f32 in LDS (R24-proven layout/staging); ef
//       TRANSPOSED [k][16 nodes] (pad-20 rows) -> one b128 same-addr
//       broadcast delivers 4 nodes' ef per k. Wave (q,m): node-quad x
//       matrix; per k = 1 b128 bcast + 1 b32 read (was 4 b32). 12 of 16
//       waves active in GEMV; G-stage via transposed H (same trick).
//       Accumulation order identical to R24 -> bit-exact.
//   K2: phases 2-4 per 16-node chunk (R24-proven, byte-identical)
//   K3: finalize with Wc1/Wc2 LDS-staged (R24-proven, byte-identical)
// Closed experiments: MFMA-K1 (R26, occupancy-starved), bf16-packed K1
// (R27, unroll-starved), fused single-dispatch (R21/R25).
// Fallbacks byte-preserved: ws>=32KB -> R17 128-block halo kernel +
// finalize; else R8 single-block.

#define NN    4096
#define CHK   32            // R17 fallback: chunk nodes
#define EXT   48            // R17 fallback: chunk + 2*8 halo
#define PEXT  40            // R17 fallback: chunk + 2*4 halo
#define NGRID 128           // R17 fallback grid
#define WS_R17 (NGRID * 64u * 4u)

#define NBLK2 256           // pipeline grid (16 nodes/block)
#define PEXT2 24            // 16 + 2*4
#define WS_PIPE ((3u * NN * 64u + NBLK2 * 64u) * 4u)

struct Smem {
    float As[EXT][64];
    float Bs[EXT][64];
    float Gs[EXT][64];
    float Hs[16][64];
    float ps[PEXT][8][2];
    float dinvs[PEXT][2];
    float facs[PEXT][2];
    float red[1024];
    float pooled[64];
    float hid[128];
};

struct SmemK1 {
    float Wa[128][64];    // M1w rows 0..127   (32KB)
    float Wb[128][64];    // M1w rows 128..255 (32KB)
    float Wh[128][64];    // We                (32KB)
    float W2s[64][64];    // W2                (16KB)
    float efT[128][20];   // ef transposed [k][node], 80B rows (10KB)
    float HT2[64][20];    // relu(H) transposed [kk][node]     (5KB)
};

struct SmemK2 {
    float As[PEXT2][64];
    float Bs[32][64];
    float Gs[32][64];
    float ps[PEXT2][8][2];
    float dinvs[PEXT2][2];
    float facs[PEXT2][2];
    float red[1024];
};

struct SmemFin {
    float Wc1s[64][128];
    float Wc2s[128][8];
    float red[256];
    float pooled[64];
    float hid[128];
};

template <bool F32>
static __device__ __forceinline__ float ldv(const void* p, int i) {
    if constexpr (F32) return ((const float*)p)[i];
    else return __bfloat162float(((const __hip_bfloat16*)p)[i]);
}

static __device__ __forceinline__ float ldr(const void* p, int i, bool f32) {
    if (f32) return ((const float*)p)[i];
    return __bfloat162float(((const __hip_bfloat16*)p)[i]);
}

static __device__ __forceinline__ float blo(unsigned u) {
    return __uint_as_float(u << 16);
}
static __device__ __forceinline__ float bhi(unsigned u) {
    return __uint_as_float(u & 0xFFFF0000u);
}

// ---------- R8/R17-proven halo body (fallback paths) ----------
template <bool F32>
static __device__ void body(Smem& sm,
    const void* ef, const void* We, const void* be, const void* M1w,
    const void* M1b, const void* M2w, const void* M2b, const void* W1,
    const void* W2, const void* Wc1, const void* bc1, const void* Wc2,
    const void* bc2, void* out)
{
    const int t = threadIdx.x;
    const int c = t & 63;
    const int w = t >> 6;
    const int a = (t >> 6) & 1;
    const int ms = t >> 7;

    const float m1b_c = ldv<F32>(M1b, c);
    const float m2w0  = ldv<F32>(M2w, c * 2 + 0);
    const float m2w1  = ldv<F32>(M2w, c * 2 + 1);
    const float m2b0  = ldv<F32>(M2b, 0);
    const float m2b1  = ldv<F32>(M2b, 1);
    const float cs0 = ldv<F32>(W1, 0) + ldv<F32>(W1, 2);
    const float cs1 = ldv<F32>(W1, 1) + ldv<F32>(W1, 3);
    const float bec = ldv<F32>(be, c);

    float accY = 0.f;

    for (int ch = blockIdx.x; ch < NN / CHK; ch += gridDim.x) {
        const int c0 = ch * CHK;
        for (int pp = 0; pp < EXT / 16; ++pp) {
            const int q  = pp * 16 + w;
            const int gi = (c0 - 8 + q) & (NN - 1);
            float aA = 0.f, aB = 0.f, aH = bec;
            #pragma unroll 2
            for (int k = 0; k < 128; ++k) {
                const float ev = ldv<F32>(ef, gi * 128 + k);
                aA += ev * ldv<F32>(M1w, k * 64 + c);
                aB += ev * ldv<F32>(M1w, 8192 + k * 64 + c);
                aH += ev * ldv<F32>(We, k * 64 + c);
            }
            sm.As[q][c] = aA;
            sm.Bs[q][c] = aB;
            sm.Hs[w][c] = fmaxf(aH, 0.f);
            __syncthreads();
            float aG = 0.f;
            #pragma unroll 2
            for (int k = 0; k < 64; ++k)
                aG += sm.Hs[w][k] * ldv<F32>(W2, k * 64 + c);
            sm.Gs[q][c] = aG;
            __syncthreads();
        }
        for (int pi = w; pi < PEXT * 8; pi += 16) {
            const int r  = pi >> 3;
            const int tt = pi & 7;
            const int off = (tt < 4) ? (tt - 4) : (tt - 3);
            const float h = fmaxf(sm.As[r + 4][c] + sm.Bs[r + 4 + off][c] + m1b_c, 0.f);
            float q0 = h * m2w0, q1 = h * m2w1;
            #pragma unroll
            for (int d2 = 32; d2; d2 >>= 1) {
                q0 += __shfl_xor(q0, d2);
                q1 += __shfl_xor(q1, d2);
            }
            if (c == 0) {
                sm.ps[r][tt][0] = q0 + m2b0;
                sm.ps[r][tt][1] = q1 + m2b1;
            }
        }
        __syncthreads();
        if (t < PEXT * 2) {
            const int r = t >> 1, aa = t & 1;
            float s = 0.f;
            #pragma unroll
            for (int tt = 0; tt < 8; ++tt) { const float p = sm.ps[r][tt][aa]; s += p * p; }
            const float dv = 1.f / sqrtf(fmaxf(s + 1e-5f, 1e-6f));
            sm.dinvs[r][aa] = dv;
            sm.facs[r][aa]  = 1.f - dv * dv * s;
        }
        __syncthreads();
        const float csa = a ? cs1 : cs0;
        #pragma unroll
        for (int it = 0; it < 4; ++it) {
            const int m = it * 8 + ms;
            const int r = m + 4;
            const int g = m + 8;
            const float di = sm.dinvs[r][a];
            float v = sm.facs[r][a] * sm.Gs[g][c];
            #pragma unroll
            for (int tt = 0; tt < 8; ++tt) {
                const int off = (tt < 4) ? (tt - 4) : (tt - 3);
                v += di * sm.ps[r + off][7 - tt][a] * sm.ps[r][tt][a]
                        * sm.dinvs[r + off][a] * sm.Gs[g + off][c];
            }
            const float x = csa * v;
            accY += (x > 0.f) ? x : expm1f(x);
        }
        __syncthreads();
    }

    sm.red[t] = accY;
    __syncthreads();

    if (gridDim.x > 1) {
        if (t < 64) {
            float s = 0.f;
            #pragma unroll
            for (int g2 = 0; g2 < 16; ++g2) s += sm.red[(g2 << 6) + t];
            ((float*)out)[blockIdx.x * 64 + t] = s;
        }
        return;
    }

    if (t < 64) {
        float s = 0.f;
        #pragma unroll
        for (int g2 = 0; g2 < 16; ++g2) s += sm.red[(g2 << 6) + t];
        sm.pooled[t] = s * (1.f / 8192.f);
    }
    __syncthreads();
    if (t < 128) {
        float acc = ldv<F32>(bc1, t);
        #pragma unroll 8
        for (int k = 0; k < 64; ++k) acc += sm.pooled[k] * ldv<F32>(Wc1, k * 128 + t);
        sm.hid[t] = fmaxf(acc, 0.f);
    }
    __syncthreads();
    if (t < 8) {
        float acc = ldv<F32>(bc2, t);
        #pragma unroll 8
        for (int k = 0; k < 128; ++k) acc += sm.hid[k] * ldv<F32>(Wc2, k * 8 + t);
        if constexpr (F32) ((float*)out)[t] = acc;
        else ((__hip_bfloat16*)out)[t] = __float2bfloat16(acc);
    }
}

// ---------- K1: quad-broadcast GEMVs, weights f32 in LDS ----------
__global__ __launch_bounds__(1024) void sheaf_k1(
    const void* ef, const void* We, const void* be, const void* M1w,
    const void* W2, float* A, float* B, float* G)
{
    __shared__ SmemK1 sm;
    __shared__ int flag;
    const int t = threadIdx.x, c = t & 63, w = t >> 6;
    const int base = blockIdx.x * 16;
    if (t == 0) flag = 0;
    __syncthreads();
    {
        const __hip_bfloat16* efh = (const __hip_bfloat16*)ef;
        bool big = false;
        #pragma unroll
        for (int k = 0; k < 8; ++k) {
            const float v = __bfloat162float(efh[t * 8 + k]);
            big |= !(fabsf(v) < 1e4f);
        }
        if (big) atomicOr(&flag, 1);
    }
    __syncthreads();

    if (!flag) {
        // ---- stage weights (R24-proven expansion) + transposed ef ----
        const unsigned* M1u = (const unsigned*)M1w;
        const unsigned* Weu = (const unsigned*)We;
        const unsigned* W2u = (const unsigned*)W2;
        const unsigned* efu = (const unsigned*)ef;
        #pragma unroll
        for (int rep = 0; rep < 4; ++rep) {
            const int j = rep * 1024 + t;               // j < 4096
            const int k = j >> 5, c2 = (j & 31) * 2;
            const unsigned a = M1u[j];
            sm.Wa[k][c2] = blo(a);  sm.Wa[k][c2 + 1] = bhi(a);
            const unsigned b = M1u[4096 + j];
            sm.Wb[k][c2] = blo(b);  sm.Wb[k][c2 + 1] = bhi(b);
            const unsigned h = Weu[j];
            sm.Wh[k][c2] = blo(h);  sm.Wh[k][c2 + 1] = bhi(h);
        }
        #pragma unroll
        for (int rep = 0; rep < 2; ++rep) {
            const int j = rep * 1024 + t;               // j < 2048
            const int k = j >> 5, c2 = (j & 31) * 2;
            const unsigned v = W2u[j];
            sm.W2s[k][c2] = blo(v);  sm.W2s[k][c2 + 1] = bhi(v);
        }
        {
            // ef: 1024 u32 words; word j = (node j>>6, kpair j&63)
            const int n = t >> 6, kk2 = (t & 63) * 2;
            const unsigned u = efu[(base << 6) + t];
            sm.efT[kk2][n]     = blo(u);
            sm.efT[kk2 + 1][n] = bhi(u);
        }
        __syncthreads();

        // ---- GEMV: wave = (q = w&3 node-quad, m = w>>2 matrix) ----
        const int q = w & 3, m = w >> 2;
        if (m < 3) {
            const float (*W)[64] = (m == 0) ? sm.Wa : (m == 1) ? sm.Wb : sm.Wh;
            float a0, a1, a2, a3;
            if (m == 2) { a0 = a1 = a2 = a3 = ldv<false>(be, c); }
            else        { a0 = a1 = a2 = a3 = 0.f; }
            #pragma unroll 4
            for (int k = 0; k < 128; ++k) {
                const float4 e4 = *(const float4*)&sm.efT[k][q * 4]; // bcast b128
                const float wv = W[k][c];                            // 2-way free
                a0 = fmaf(e4.x, wv, a0);
                a1 = fmaf(e4.y, wv, a1);
                a2 = fmaf(e4.z, wv, a2);
                a3 = fmaf(e4.w, wv, a3);
            }
            if (m == 0) {
                A[((base + q * 4 + 0) << 6) + c] = a0;
                A[((base + q * 4 + 1) << 6) + c] = a1;
                A[((base + q * 4 + 2) << 6) + c] = a2;
                A[((base + q * 4 + 3) << 6) + c] = a3;
            } else if (m == 1) {
                B[((base + q * 4 + 0) << 6) + c] = a0;
                B[((base + q * 4 + 1) << 6) + c] = a1;
                B[((base + q * 4 + 2) << 6) + c] = a2;
                B[((base + q * 4 + 3) << 6) + c] = a3;
            } else {
                // H transposed: HT2[kk=c][node], conflict-free (pad 20)
                sm.HT2[c][q * 4 + 0] = fmaxf(a0, 0.f);
                sm.HT2[c][q * 4 + 1] = fmaxf(a1, 0.f);
                sm.HT2[c][q * 4 + 2] = fmaxf(a2, 0.f);
                sm.HT2[c][q * 4 + 3] = fmaxf(a3, 0.f);
            }
        }
        __syncthreads();

        // ---- G = relu(H) @ W2: waves 0..3 (q = w), quad-bcast again ----
        if (w < 4) {
            float g0 = 0.f, g1 = 0.f, g2 = 0.f, g3 = 0.f;
            #pragma unroll 4
            for (int kk = 0; kk < 64; ++kk) {
                const float4 h4 = *(const float4*)&sm.HT2[kk][w * 4];
                const float wv = sm.W2s[kk][c];
                g0 = fmaf(h4.x, wv, g0);
                g1 = fmaf(h4.y, wv, g1);
                g2 = fmaf(h4.z, wv, g2);
                g3 = fmaf(h4.w, wv, g3);
            }
            G[((base + w * 4 + 0) << 6) + c] = g0;
            G[((base + w * 4 + 1) << 6) + c] = g1;
            G[((base + w * 4 + 2) << 6) + c] = g2;
            G[((base + w * 4 + 3) << 6) + c] = g3;
        }
    } else {
        // ---- f32 path (never triggers in practice): direct loops ----
        const float* eff = (const float*)ef;
        const float* M1f = (const float*)M1w;
        const float* Wef = (const float*)We;
        for (int o = t; o < 16 * 192; o += 1024) {
            const int n = o / 192, j = o % 192;
            float s = (j >= 128) ? ((const float*)be)[j - 128] : 0.f;
            for (int k = 0; k < 128; ++k) {
                const float e = eff[(base + n) * 128 + k];
                const float wv = (j < 64) ? M1f[k * 64 + j]
                               : (j < 128) ? M1f[8192 + k * 64 + (j - 64)]
                               : Wef[k * 64 + (j - 128)];
                s += e * wv;
            }
            if (j < 64) A[(base + n) * 64 + j] = s;
            else if (j < 128) B[(base + n) * 64 + (j - 64)] = s;
            else sm.HT2[j - 128][n] = fmaxf(s, 0.f);
        }
        __syncthreads();
        const float* W2f = (const float*)W2;
        for (int o = t; o < 16 * 64; o += 1024) {
            const int n = o >> 6, cc = o & 63;
            float s = 0.f;
            for (int k = 0; k < 64; ++k) s += sm.HT2[k][n] * W2f[k * 64 + cc];
            G[(base + n) * 64 + cc] = s;
        }
    }
}

// ---------- K2: sheaf stencil phases 2-4 (R24-proven) ----------
template <bool F32>
static __device__ void k2body(SmemK2& sm,
    const void* M1b, const void* M2w, const void* M2b, const void* W1,
    const float* A, const float* B, const float* G, float* partials)
{
    const int t = threadIdx.x, c = t & 63, w = t >> 6;
    const int base = blockIdx.x * 16;

    for (int idx = t; idx < PEXT2 * 64; idx += 1024) {
        const int r = idx >> 6, cc = idx & 63;
        sm.As[r][cc] = A[(((base - 4 + r) & (NN - 1)) << 6) + cc];
    }
    for (int idx = t; idx < 32 * 64; idx += 1024) {
        const int r = idx >> 6, cc = idx & 63;
        const int gi = ((base - 8 + r) & (NN - 1)) << 6;
        sm.Bs[r][cc] = B[gi + cc];
        sm.Gs[r][cc] = G[gi + cc];
    }
    __syncthreads();

    const float m1b_c = ldv<F32>(M1b, c);
    const float m2w0  = ldv<F32>(M2w, c * 2 + 0);
    const float m2w1  = ldv<F32>(M2w, c * 2 + 1);
    const float m2b0  = ldv<F32>(M2b, 0);
    const float m2b1  = ldv<F32>(M2b, 1);
    const float cs0 = ldv<F32>(W1, 0) + ldv<F32>(W1, 2);
    const float cs1 = ldv<F32>(W1, 1) + ldv<F32>(W1, 3);

    for (int pi = w; pi < PEXT2 * 8; pi += 16) {
        const int r  = pi >> 3;
        const int tt = pi & 7;
        const int off = (tt < 4) ? (tt - 4) : (tt - 3);
        const float h = fmaxf(sm.As[r][c] + sm.Bs[r + 4 + off][c] + m1b_c, 0.f);
        float q0 = h * m2w0, q1 = h * m2w1;
        #pragma unroll
        for (int d2 = 32; d2; d2 >>= 1) {
            q0 += __shfl_xor(q0, d2);
            q1 += __shfl_xor(q1, d2);
        }
        if (c == 0) {
            sm.ps[r][tt][0] = q0 + m2b0;
            sm.ps[r][tt][1] = q1 + m2b1;
        }
    }
    __syncthreads();

    if (t < PEXT2 * 2) {
        const int r = t >> 1, aa = t & 1;
        float s = 0.f;
        #pragma unroll
        for (int tt = 0; tt < 8; ++tt) { const float p = sm.ps[r][tt][aa]; s += p * p; }
        const float dv = 1.f / sqrtf(fmaxf(s + 1e-5f, 1e-6f));
        sm.dinvs[r][aa] = dv;
        sm.facs[r][aa]  = 1.f - dv * dv * s;
    }
    __syncthreads();

    float accY = 0.f;
    #pragma unroll
    for (int it = 0; it < 2; ++it) {
        const int m = it * 8 + (t >> 7);
        const int a = (t >> 6) & 1;
        const int r = m + 4;
        const int g = m + 8;
        const float csa = a ? cs1 : cs0;
        const float di = sm.dinvs[r][a];
        float v = sm.facs[r][a] * sm.Gs[g][c];
        #pragma unroll
        for (int tt = 0; tt < 8; ++tt) {
            const int off = (tt < 4) ? (tt - 4) : (tt - 3);
            v += di * sm.ps[r + off][7 - tt][a] * sm.ps[r][tt][a]
                    * sm.dinvs[r + off][a] * sm.Gs[g + off][c];
        }
        const float x = csa * v;
        accY += (x > 0.f) ? x : expm1f(x);
    }

    sm.red[t] = accY;
    __syncthreads();
    if (t < 64) {
        float s = 0.f;
        #pragma unroll
        for (int g2 = 0; g2 < 16; ++g2) s += sm.red[(g2 << 6) + t];
        partials[blockIdx.x * 64 + t] = s;
    }
}

__global__ __launch_bounds__(1024) void sheaf_k2(
    const void* ef, const void* M1b, const void* M2w, const void* M2b,
    const void* W1, const float* A, const float* B, const float* G,
    float* partials)
{
    __shared__ SmemK2 sm;
    __shared__ int flag;
    const int t = threadIdx.x;
    if (t == 0) flag = 0;
    __syncthreads();
    {
        const __hip_bfloat16* efh = (const __hip_bfloat16*)ef;
        bool big = false;
        #pragma unroll
        for (int k = 0; k < 8; ++k) {
            const float v = __bfloat162float(efh[t * 8 + k]);
            big |= !(fabsf(v) < 1e4f);
        }
        if (big) atomicOr(&flag, 1);
    }
    __syncthreads();
    if (flag) k2body<true >(sm, M1b, M2w, M2b, W1, A, B, G, partials);
    else      k2body<false>(sm, M1b, M2w, M2b, W1, A, B, G, partials);
}

// ---------- finalize: Wc1/Wc2 LDS-staged reduce + classifier ----------
template <bool F32>
static __device__ void finbody(SmemFin& sm,
    const void* Wc1, const void* bc1, const void* Wc2, const void* bc2,
    const float* partials, int nparts, void* out)
{
    const int t = threadIdx.x;

    if constexpr (F32) {
        for (int idx = t; idx < 64 * 128; idx += 256)
            sm.Wc1s[idx >> 7][idx & 127] = ((const float*)Wc1)[idx];
        for (int idx = t; idx < 128 * 8; idx += 256)
            sm.Wc2s[idx >> 3][idx & 7] = ((const float*)Wc2)[idx];
    } else {
        for (int j = t; j < 4096; j += 256) {
            const int k = j >> 6, c2 = (j & 63) * 2;
            const unsigned u = ((const unsigned*)Wc1)[j];
            sm.Wc1s[k][c2] = blo(u);  sm.Wc1s[k][c2 + 1] = bhi(u);
        }
        for (int j = t; j < 512; j += 256) {
            const int k = j >> 2, c2 = (j & 3) * 2;
            const unsigned u = ((const unsigned*)Wc2)[j];
            sm.Wc2s[k][c2] = blo(u);  sm.Wc2s[k][c2 + 1] = bhi(u);
        }
    }

    const int h = t & 63, g = t >> 6;
    float s = 0.f;
    for (int b = g; b < nparts; b += 4) s += partials[b * 64 + h];
    sm.red[t] = s;
    __syncthreads();
    if (t < 64)
        sm.pooled[t] = (sm.red[t] + sm.red[t + 64] + sm.red[t + 128] + sm.red[t + 192])
                       * (1.f / 8192.f);
    __syncthreads();
    if (t < 128) {
        float acc = ldv<F32>(bc1, t);
        #pragma unroll 8
        for (int k = 0; k < 64; ++k) acc = fmaf(sm.pooled[k], sm.Wc1s[k][t], acc);
        sm.hid[t] = fmaxf(acc, 0.f);
    }
    __syncthreads();
    if (t < 8) {
        float acc = ldv<F32>(bc2, t);
        #pragma unroll 8
        for (int k = 0; k < 128; ++k) acc = fmaf(sm.hid[k], sm.Wc2s[k][t], acc);
        if constexpr (F32) ((float*)out)[t] = acc;
        else ((__hip_bfloat16*)out)[t] = __float2bfloat16(acc);
    }
}

__global__ __launch_bounds__(256) void sheaf_finalize(
    const void* ef, const void* Wc1, const void* bc1, const void* Wc2,
    const void* bc2, const float* partials, int nparts, void* out)
{
    __shared__ SmemFin sm;
    __shared__ int flag;
    const int t = threadIdx.x;
    if (t == 0) flag = 0;
    __syncthreads();
    {
        const __hip_bfloat16* efh = (const __hip_bfloat16*)ef;
        bool big = false;
        #pragma unroll
        for (int k = 0; k < 8; ++k) {
            const float v = __bfloat162float(efh[t * 8 + k]);
            big |= !(fabsf(v) < 1e4f);
        }
        if (big) atomicOr(&flag, 1);
    }
    __syncthreads();
    if (flag) finbody<true >(sm, Wc1, bc1, Wc2, bc2, partials, nparts, out);
    else      finbody<false>(sm, Wc1, bc1, Wc2, bc2, partials, nparts, out);
}

__global__ __launch_bounds__(1024) void SheafConvolutionalNetwork_81698867905240_kernel(
    const void* ef, const void* We, const void* be, const void* M1w,
    const void* M1b, const void* M2w, const void* M2b, const void* W1,
    const void* W2, const void* Wc1, const void* bc1, const void* Wc2,
    const void* bc2, void* out)
{
    __shared__ Smem sm;
    __shared__ int flag;
    const int t = threadIdx.x;
    if (t == 0) flag = 0;
    __syncthreads();
    {
        const __hip_bfloat16* efh = (const __hip_bfloat16*)ef;
        bool big = false;
        #pragma unroll
        for (int k = 0; k < 8; ++k) {
            const float v = __bfloat162float(efh[t * 8 + k]);
            big |= !(fabsf(v) < 1e4f);
        }
        if (big) atomicOr(&flag, 1);
    }
    __syncthreads();
    if (flag)
        body<true >(sm, ef, We, be, M1w, M1b, M2w, M2b, W1, W2, Wc1, bc1, Wc2, bc2, out);
    else
        body<false>(sm, ef, We, be, M1w, M1b, M2w, M2b, W1, W2, Wc1, bc1, Wc2, bc2, out);
}

extern "C" void kernel_launch(void* const* d_in, const int* in_sizes, int n_in,
                              void* d_out, int out_size, void* d_ws, size_t ws_size,
                              hipStream_t stream)
{
    (void)in_sizes; (void)n_in; (void)out_size;
    (void)hipGetLastError();   // clear stale error

    if (d_ws != nullptr && ws_size >= (size_t)WS_PIPE) {
        float* A = (float*)d_ws;
        float* B = A + NN * 64;
        float* G = B + NN * 64;
        float* partials = G + NN * 64;
        sheaf_k1<<<dim3(NBLK2), dim3(1024), 0, stream>>>(
            d_in[0], d_in[1], d_in[2], d_in[3], d_in[8], A, B, G);
        sheaf_k2<<<dim3(NBLK2), dim3(1024), 0, stream>>>(
            d_in[0], d_in[4], d_in[5], d_in[6], d_in[7], A, B, G, partials);
        sheaf_finalize<<<dim3(1), dim3(256), 0, stream>>>(
            d_in[0], d_in[9], d_in[10], d_in[11], d_in[12],
            partials, NBLK2, d_out);
    } else if (d_ws != nullptr && ws_size >= (size_t)WS_R17) {
        SheafConvolutionalNetwork_81698867905240_kernel<<<dim3(NGRID), dim3(1024), 0, stream>>>(
            d_in[0], d_in[1], d_in[2], d_in[3], d_in[4], d_in[5], d_in[6],
            d_in[7], d_in[8], d_in[9], d_in[10], d_in[11], d_in[12], d_ws);
        sheaf_finalize<<<dim3(1), dim3(256), 0, stream>>>(
            d_in[0], d_in[9], d_in[10], d_in[11], d_in[12],
            (const float*)d_ws, NGRID, d_out);
    } else {
        SheafConvolutionalNetwork_81698867905240_kernel<<<dim3(1), dim3(1024), 0, stream>>>(
            d_in[0], d_in[1], d_in[2], d_in[3], d_in[4], d_in[5], d_in[6],
            d_in[7], d_in[8], d_in[9], d_in[10], d_in[11], d_in[12], d_out);
    }

    if (hipGetLastError() != hipSuccess)
        (void)hipMemsetAsync(d_out, 0x41, 16, stream);
}

// Round 29
// 53.646 us; speedup vs baseline: 2.6456x; 1.4115x over previous
//
#include <hip/hip_runtime.h>
#include <hip/hip_bf16.h>

// Sheaf CNN on the fixed ring graph (offsets ±1..4 mod 4096, degree 8).
// 3-dispatch pipeline, weights-in-LDS edition (R24-proven, 53.8us):
//   K1: stage M1w/We/W2 as f32 in LDS (124KB) -> per-wave GEMV reads LDS
//       only (b32 broadcast + 2-way b32, the proven-fast pattern); A,B,G.
//   K2: phases 2-4 per 16-node chunk
//   K3: finalize with Wc1/Wc2 LDS-staged; fixed-order reduce + classifier.
// Closed: MFMA-K1 (R26), bf16-packed K1 (R27), quad-bcast-b128 K1 (R28 --
// same-addr ds_read_b128 is NOT broadcast-optimized), fused (R21/R25).
// Fallbacks byte-preserved: ws>=32KB -> R17 128-block halo kernel +
// finalize; else R8 single-block.

#define NN    4096
#define CHK   32            // R17 fallback: chunk nodes
#define EXT   48            // R17 fallback: chunk + 2*8 halo
#define PEXT  40            // R17 fallback: chunk + 2*4 halo
#define NGRID 128           // R17 fallback grid
#define WS_R17 (NGRID * 64u * 4u)

#define NBLK2 256           // pipeline grid (16 nodes/block)
#define PEXT2 24            // 16 + 2*4
#define WS_PIPE ((3u * NN * 64u + NBLK2 * 64u) * 4u)

struct Smem {
    float As[EXT][64];
    float Bs[EXT][64];
    float Gs[EXT][64];
    float Hs[16][64];
    float ps[PEXT][8][2];
    float dinvs[PEXT][2];
    float facs[PEXT][2];
    float red[1024];
    float pooled[64];
    float hid[128];
};

struct SmemK1 {
    float Wa[128][64];    // M1w rows 0..127   (32KB)
    float Wb[128][64];    // M1w rows 128..255 (32KB)
    float Wh[128][64];    // We                (32KB)
    float W2s[64][64];    // W2                (16KB)
    float efs[16][128];   // ef rows           (8KB)
    float Hs[16][64];     // relu(ef@We+be)    (4KB)
};

struct SmemK2 {
    float As[PEXT2][64];
    float Bs[32][64];
    float Gs[32][64];
    float ps[PEXT2][8][2];
    float dinvs[PEXT2][2];
    float facs[PEXT2][2];
    float red[1024];
};

struct SmemFin {
    float Wc1s[64][128];  // 32KB
    float Wc2s[128][8];   // 4KB
    float red[256];
    float pooled[64];
    float hid[128];
};

template <bool F32>
static __device__ __forceinline__ float ldv(const void* p, int i) {
    if constexpr (F32) return ((const float*)p)[i];
    else return __bfloat162float(((const __hip_bfloat16*)p)[i]);
}

static __device__ __forceinline__ float ldr(const void* p, int i, bool f32) {
    if (f32) return ((const float*)p)[i];
    return __bfloat162float(((const __hip_bfloat16*)p)[i]);
}

static __device__ __forceinline__ float blo(unsigned u) {
    return __uint_as_float(u << 16);
}
static __device__ __forceinline__ float bhi(unsigned u) {
    return __uint_as_float(u & 0xFFFF0000u);
}

// ---------- R8/R17-proven halo body (fallback paths) ----------
template <bool F32>
static __device__ void body(Smem& sm,
    const void* ef, const void* We, const void* be, const void* M1w,
    const void* M1b, const void* M2w, const void* M2b, const void* W1,
    const void* W2, const void* Wc1, const void* bc1, const void* Wc2,
    const void* bc2, void* out)
{
    const int t = threadIdx.x;
    const int c = t & 63;
    const int w = t >> 6;
    const int a = (t >> 6) & 1;
    const int ms = t >> 7;

    const float m1b_c = ldv<F32>(M1b, c);
    const float m2w0  = ldv<F32>(M2w, c * 2 + 0);
    const float m2w1  = ldv<F32>(M2w, c * 2 + 1);
    const float m2b0  = ldv<F32>(M2b, 0);
    const float m2b1  = ldv<F32>(M2b, 1);
    const float cs0 = ldv<F32>(W1, 0) + ldv<F32>(W1, 2);
    const float cs1 = ldv<F32>(W1, 1) + ldv<F32>(W1, 3);
    const float bec = ldv<F32>(be, c);

    float accY = 0.f;

    for (int ch = blockIdx.x; ch < NN / CHK; ch += gridDim.x) {
        const int c0 = ch * CHK;
        for (int pp = 0; pp < EXT / 16; ++pp) {
            const int q  = pp * 16 + w;
            const int gi = (c0 - 8 + q) & (NN - 1);
            float aA = 0.f, aB = 0.f, aH = bec;
            #pragma unroll 2
            for (int k = 0; k < 128; ++k) {
                const float ev = ldv<F32>(ef, gi * 128 + k);
                aA += ev * ldv<F32>(M1w, k * 64 + c);
                aB += ev * ldv<F32>(M1w, 8192 + k * 64 + c);
                aH += ev * ldv<F32>(We, k * 64 + c);
            }
            sm.As[q][c] = aA;
            sm.Bs[q][c] = aB;
            sm.Hs[w][c] = fmaxf(aH, 0.f);
            __syncthreads();
            float aG = 0.f;
            #pragma unroll 2
            for (int k = 0; k < 64; ++k)
                aG += sm.Hs[w][k] * ldv<F32>(W2, k * 64 + c);
            sm.Gs[q][c] = aG;
            __syncthreads();
        }
        for (int pi = w; pi < PEXT * 8; pi += 16) {
            const int r  = pi >> 3;
            const int tt = pi & 7;
            const int off = (tt < 4) ? (tt - 4) : (tt - 3);
            const float h = fmaxf(sm.As[r + 4][c] + sm.Bs[r + 4 + off][c] + m1b_c, 0.f);
            float q0 = h * m2w0, q1 = h * m2w1;
            #pragma unroll
            for (int d2 = 32; d2; d2 >>= 1) {
                q0 += __shfl_xor(q0, d2);
                q1 += __shfl_xor(q1, d2);
            }
            if (c == 0) {
                sm.ps[r][tt][0] = q0 + m2b0;
                sm.ps[r][tt][1] = q1 + m2b1;
            }
        }
        __syncthreads();
        if (t < PEXT * 2) {
            const int r = t >> 1, aa = t & 1;
            float s = 0.f;
            #pragma unroll
            for (int tt = 0; tt < 8; ++tt) { const float p = sm.ps[r][tt][aa]; s += p * p; }
            const float dv = 1.f / sqrtf(fmaxf(s + 1e-5f, 1e-6f));
            sm.dinvs[r][aa] = dv;
            sm.facs[r][aa]  = 1.f - dv * dv * s;
        }
        __syncthreads();
        const float csa = a ? cs1 : cs0;
        #pragma unroll
        for (int it = 0; it < 4; ++it) {
            const int m = it * 8 + ms;
            const int r = m + 4;
            const int g = m + 8;
            const float di = sm.dinvs[r][a];
            float v = sm.facs[r][a] * sm.Gs[g][c];
            #pragma unroll
            for (int tt = 0; tt < 8; ++tt) {
                const int off = (tt < 4) ? (tt - 4) : (tt - 3);
                v += di * sm.ps[r + off][7 - tt][a] * sm.ps[r][tt][a]
                        * sm.dinvs[r + off][a] * sm.Gs[g + off][c];
            }
            const float x = csa * v;
            accY += (x > 0.f) ? x : expm1f(x);
        }
        __syncthreads();
    }

    sm.red[t] = accY;
    __syncthreads();

    if (gridDim.x > 1) {
        if (t < 64) {
            float s = 0.f;
            #pragma unroll
            for (int g2 = 0; g2 < 16; ++g2) s += sm.red[(g2 << 6) + t];
            ((float*)out)[blockIdx.x * 64 + t] = s;
        }
        return;
    }

    if (t < 64) {
        float s = 0.f;
        #pragma unroll
        for (int g2 = 0; g2 < 16; ++g2) s += sm.red[(g2 << 6) + t];
        sm.pooled[t] = s * (1.f / 8192.f);
    }
    __syncthreads();
    if (t < 128) {
        float acc = ldv<F32>(bc1, t);
        #pragma unroll 8
        for (int k = 0; k < 64; ++k) acc += sm.pooled[k] * ldv<F32>(Wc1, k * 128 + t);
        sm.hid[t] = fmaxf(acc, 0.f);
    }
    __syncthreads();
    if (t < 8) {
        float acc = ldv<F32>(bc2, t);
        #pragma unroll 8
        for (int k = 0; k < 128; ++k) acc += sm.hid[k] * ldv<F32>(Wc2, k * 8 + t);
        if constexpr (F32) ((float*)out)[t] = acc;
        else ((__hip_bfloat16*)out)[t] = __float2bfloat16(acc);
    }
}

// ---------- K1: node GEMVs with weights in LDS ----------
template <bool F32>
static __device__ void k1body(SmemK1& sm,
    const void* ef, const void* We, const void* be, const void* M1w,
    const void* W2, float* A, float* B, float* G)
{
    const int t = threadIdx.x, c = t & 63, w = t >> 6;
    const int base = blockIdx.x * 16;

    // ---- stage weights into LDS (coalesced, independent loads) ----
    if constexpr (F32) {
        for (int idx = t; idx < 128 * 64; idx += 1024) {
            const int k = idx >> 6, cc = idx & 63;
            sm.Wa[k][cc] = ((const float*)M1w)[idx];
            sm.Wb[k][cc] = ((const float*)M1w)[8192 + idx];
            sm.Wh[k][cc] = ((const float*)We)[idx];
        }
        for (int idx = t; idx < 64 * 64; idx += 1024)
            sm.W2s[idx >> 6][idx & 63] = ((const float*)W2)[idx];
        for (int idx = t; idx < 16 * 128; idx += 1024)
            sm.efs[idx >> 7][idx & 127] = ((const float*)ef)[(base << 7) + idx];
    } else {
        for (int j = t; j < 4096; j += 1024) {          // 128 rows x 32 words
            const int k = j >> 5, c2 = (j & 31) * 2;
            const unsigned a = ((const unsigned*)M1w)[j];
            sm.Wa[k][c2] = blo(a);  sm.Wa[k][c2 + 1] = bhi(a);
            const unsigned b = ((const unsigned*)M1w)[4096 + j];
            sm.Wb[k][c2] = blo(b);  sm.Wb[k][c2 + 1] = bhi(b);
            const unsigned h = ((const unsigned*)We)[j];
            sm.Wh[k][c2] = blo(h);  sm.Wh[k][c2 + 1] = bhi(h);
        }
        for (int j = t; j < 2048; j += 1024) {          // 64 rows x 32 words
            const int k = j >> 5, c2 = (j & 31) * 2;
            const unsigned v = ((const unsigned*)W2)[j];
            sm.W2s[k][c2] = blo(v);  sm.W2s[k][c2 + 1] = bhi(v);
        }
        for (int j = t; j < 16 * 64; j += 1024) {       // ef: 16 rows x 64 words
            const int n = j >> 6, kk = (j & 63) * 2;
            const unsigned u = ((const unsigned*)ef)[(base << 6) + j];
            sm.efs[n][kk] = blo(u);  sm.efs[n][kk + 1] = bhi(u);
        }
    }
    __syncthreads();

    // ---- GEMV: wave w owns node base+w; all operands in LDS ----
    const int n = w;
    float aA = 0.f, aB = 0.f, aH = ldv<F32>(be, c);
    #pragma unroll 8
    for (int k = 0; k < 128; ++k) {
        const float e = sm.efs[n][k];                   // broadcast (free)
        aA = fmaf(e, sm.Wa[k][c], aA);                  // 2-way bank (free)
        aB = fmaf(e, sm.Wb[k][c], aB);
        aH = fmaf(e, sm.Wh[k][c], aH);
    }
    A[((base + n) << 6) + c] = aA;
    B[((base + n) << 6) + c] = aB;
    sm.Hs[n][c] = fmaxf(aH, 0.f);
    __syncthreads();

    float aG = 0.f;
    #pragma unroll 8
    for (int k = 0; k < 64; ++k)
        aG = fmaf(sm.Hs[n][k], sm.W2s[k][c], aG);
    G[((base + n) << 6) + c] = aG;
}

__global__ __launch_bounds__(1024) void sheaf_k1(
    const void* ef, const void* We, const void* be, const void* M1w,
    const void* W2, float* A, float* B, float* G)
{
    __shared__ SmemK1 sm;
    __shared__ int flag;
    const int t = threadIdx.x;
    if (t == 0) flag = 0;
    __syncthreads();
    {
        const __hip_bfloat16* efh = (const __hip_bfloat16*)ef;
        bool big = false;
        #pragma unroll
        for (int k = 0; k < 8; ++k) {
            const float v = __bfloat162float(efh[t * 8 + k]);
            big |= !(fabsf(v) < 1e4f);
        }
        if (big) atomicOr(&flag, 1);
    }
    __syncthreads();
    if (flag) k1body<true >(sm, ef, We, be, M1w, W2, A, B, G);
    else      k1body<false>(sm, ef, We, be, M1w, W2, A, B, G);
}

// ---------- K2: sheaf stencil phases 2-4 (R19-proven) ----------
template <bool F32>
static __device__ void k2body(SmemK2& sm,
    const void* M1b, const void* M2w, const void* M2b, const void* W1,
    const float* A, const float* B, const float* G, float* partials)
{
    const int t = threadIdx.x, c = t & 63, w = t >> 6;
    const int base = blockIdx.x * 16;

    for (int idx = t; idx < PEXT2 * 64; idx += 1024) {
        const int r = idx >> 6, cc = idx & 63;
        sm.As[r][cc] = A[(((base - 4 + r) & (NN - 1)) << 6) + cc];
    }
    for (int idx = t; idx < 32 * 64; idx += 1024) {
        const int r = idx >> 6, cc = idx & 63;
        const int gi = ((base - 8 + r) & (NN - 1)) << 6;
        sm.Bs[r][cc] = B[gi + cc];
        sm.Gs[r][cc] = G[gi + cc];
    }
    __syncthreads();

    const float m1b_c = ldv<F32>(M1b, c);
    const float m2w0  = ldv<F32>(M2w, c * 2 + 0);
    const float m2w1  = ldv<F32>(M2w, c * 2 + 1);
    const float m2b0  = ldv<F32>(M2b, 0);
    const float m2b1  = ldv<F32>(M2b, 1);
    const float cs0 = ldv<F32>(W1, 0) + ldv<F32>(W1, 2);
    const float cs1 = ldv<F32>(W1, 1) + ldv<F32>(W1, 3);

    for (int pi = w; pi < PEXT2 * 8; pi += 16) {
        const int r  = pi >> 3;
        const int tt = pi & 7;
        const int off = (tt < 4) ? (tt - 4) : (tt - 3);
        const float h = fmaxf(sm.As[r][c] + sm.Bs[r + 4 + off][c] + m1b_c, 0.f);
        float q0 = h * m2w0, q1 = h * m2w1;
        #pragma unroll
        for (int d2 = 32; d2; d2 >>= 1) {
            q0 += __shfl_xor(q0, d2);
            q1 += __shfl_xor(q1, d2);
        }
        if (c == 0) {
            sm.ps[r][tt][0] = q0 + m2b0;
            sm.ps[r][tt][1] = q1 + m2b1;
        }
    }
    __syncthreads();

    if (t < PEXT2 * 2) {
        const int r = t >> 1, aa = t & 1;
        float s = 0.f;
        #pragma unroll
        for (int tt = 0; tt < 8; ++tt) { const float p = sm.ps[r][tt][aa]; s += p * p; }
        const float dv = 1.f / sqrtf(fmaxf(s + 1e-5f, 1e-6f));
        sm.dinvs[r][aa] = dv;
        sm.facs[r][aa]  = 1.f - dv * dv * s;
    }
    __syncthreads();

    float accY = 0.f;
    #pragma unroll
    for (int it = 0; it < 2; ++it) {
        const int m = it * 8 + (t >> 7);
        const int a = (t >> 6) & 1;
        const int r = m + 4;
        const int g = m + 8;
        const float csa = a ? cs1 : cs0;
        const float di = sm.dinvs[r][a];
        float v = sm.facs[r][a] * sm.Gs[g][c];
        #pragma unroll
        for (int tt = 0; tt < 8; ++tt) {
            const int off = (tt < 4) ? (tt - 4) : (tt - 3);
            v += di * sm.ps[r + off][7 - tt][a] * sm.ps[r][tt][a]
                    * sm.dinvs[r + off][a] * sm.Gs[g + off][c];
        }
        const float x = csa * v;
        accY += (x > 0.f) ? x : expm1f(x);
    }

    sm.red[t] = accY;
    __syncthreads();
    if (t < 64) {
        float s = 0.f;
        #pragma unroll
        for (int g2 = 0; g2 < 16; ++g2) s += sm.red[(g2 << 6) + t];
        partials[blockIdx.x * 64 + t] = s;
    }
}

__global__ __launch_bounds__(1024) void sheaf_k2(
    const void* ef, const void* M1b, const void* M2w, const void* M2b,
    const void* W1, const float* A, const float* B, const float* G,
    float* partials)
{
    __shared__ SmemK2 sm;
    __shared__ int flag;
    const int t = threadIdx.x;
    if (t == 0) flag = 0;
    __syncthreads();
    {
        const __hip_bfloat16* efh = (const __hip_bfloat16*)ef;
        bool big = false;
        #pragma unroll
        for (int k = 0; k < 8; ++k) {
            const float v = __bfloat162float(efh[t * 8 + k]);
            big |= !(fabsf(v) < 1e4f);
        }
        if (big) atomicOr(&flag, 1);
    }
    __syncthreads();
    if (flag) k2body<true >(sm, M1b, M2w, M2b, W1, A, B, G, partials);
    else      k2body<false>(sm, M1b, M2w, M2b, W1, A, B, G, partials);
}

// ---------- finalize: Wc1/Wc2 LDS-staged reduce + classifier ----------
template <bool F32>
static __device__ void finbody(SmemFin& sm,
    const void* Wc1, const void* bc1, const void* Wc2, const void* bc2,
    const float* partials, int nparts, void* out)
{
    const int t = threadIdx.x;

    // stage classifier weights (coalesced, independent loads)
    if constexpr (F32) {
        for (int idx = t; idx < 64 * 128; idx += 256)
            sm.Wc1s[idx >> 7][idx & 127] = ((const float*)Wc1)[idx];
        for (int idx = t; idx < 128 * 8; idx += 256)
            sm.Wc2s[idx >> 3][idx & 7] = ((const float*)Wc2)[idx];
    } else {
        for (int j = t; j < 4096; j += 256) {           // 64 rows x 64 words
            const int k = j >> 6, c2 = (j & 63) * 2;
            const unsigned u = ((const unsigned*)Wc1)[j];
            sm.Wc1s[k][c2] = blo(u);  sm.Wc1s[k][c2 + 1] = bhi(u);
        }
        for (int j = t; j < 512; j += 256) {            // 128 rows x 4 words
            const int k = j >> 2, c2 = (j & 3) * 2;
            const unsigned u = ((const unsigned*)Wc2)[j];
            sm.Wc2s[k][c2] = blo(u);  sm.Wc2s[k][c2 + 1] = bhi(u);
        }
    }

    // fixed-order reduce of partials (independent coalesced loads)
    const int h = t & 63, g = t >> 6;
    float s = 0.f;
    for (int b = g; b < nparts; b += 4) s += partials[b * 64 + h];
    sm.red[t] = s;
    __syncthreads();
    if (t < 64)
        sm.pooled[t] = (sm.red[t] + sm.red[t + 64] + sm.red[t + 128] + sm.red[t + 192])
                       * (1.f / 8192.f);
    __syncthreads();
    if (t < 128) {
        float acc = ldv<F32>(bc1, t);
        #pragma unroll 8
        for (int k = 0; k < 64; ++k) acc = fmaf(sm.pooled[k], sm.Wc1s[k][t], acc);
        sm.hid[t] = fmaxf(acc, 0.f);
    }
    __syncthreads();
    if (t < 8) {
        float acc = ldv<F32>(bc2, t);
        #pragma unroll 8
        for (int k = 0; k < 128; ++k) acc = fmaf(sm.hid[k], sm.Wc2s[k][t], acc);
        if constexpr (F32) ((float*)out)[t] = acc;
        else ((__hip_bfloat16*)out)[t] = __float2bfloat16(acc);
    }
}

__global__ __launch_bounds__(256) void sheaf_finalize(
    const void* ef, const void* Wc1, const void* bc1, const void* Wc2,
    const void* bc2, const float* partials, int nparts, void* out)
{
    __shared__ SmemFin sm;
    __shared__ int flag;
    const int t = threadIdx.x;
    if (t == 0) flag = 0;
    __syncthreads();
    {
        const __hip_bfloat16* efh = (const __hip_bfloat16*)ef;
        bool big = false;
        #pragma unroll
        for (int k = 0; k < 8; ++k) {
            const float v = __bfloat162float(efh[t * 8 + k]);
            big |= !(fabsf(v) < 1e4f);
        }
        if (big) atomicOr(&flag, 1);
    }
    __syncthreads();
    if (flag) finbody<true >(sm, Wc1, bc1, Wc2, bc2, partials, nparts, out);
    else      finbody<false>(sm, Wc1, bc1, Wc2, bc2, partials, nparts, out);
}

__global__ __launch_bounds__(1024) void SheafConvolutionalNetwork_81698867905240_kernel(
    const void* ef, const void* We, const void* be, const void* M1w,
    const void* M1b, const void* M2w, const void* M2b, const void* W1,
    const void* W2, const void* Wc1, const void* bc1, const void* Wc2,
    const void* bc2, void* out)
{
    __shared__ Smem sm;
    __shared__ int flag;
    const int t = threadIdx.x;
    if (t == 0) flag = 0;
    __syncthreads();
    {
        const __hip_bfloat16* efh = (const __hip_bfloat16*)ef;
        bool big = false;
        #pragma unroll
        for (int k = 0; k < 8; ++k) {
            const float v = __bfloat162float(efh[t * 8 + k]);
            big |= !(fabsf(v) < 1e4f);
        }
        if (big) atomicOr(&flag, 1);
    }
    __syncthreads();
    if (flag)
        body<true >(sm, ef, We, be, M1w, M1b, M2w, M2b, W1, W2, Wc1, bc1, Wc2, bc2, out);
    else
        body<false>(sm, ef, We, be, M1w, M1b, M2w, M2b, W1, W2, Wc1, bc1, Wc2, bc2, out);
}

extern "C" void kernel_launch(void* const* d_in, const int* in_sizes, int n_in,
                              void* d_out, int out_size, void* d_ws, size_t ws_size,
                              hipStream_t stream)
{
    (void)in_sizes; (void)n_in; (void)out_size;
    (void)hipGetLastError();   // clear stale error

    if (d_ws != nullptr && ws_size >= (size_t)WS_PIPE) {
        float* A = (float*)d_ws;
        float* B = A + NN * 64;
        float* G = B + NN * 64;
        float* partials = G + NN * 64;
        sheaf_k1<<<dim3(NBLK2), dim3(1024), 0, stream>>>(
            d_in[0], d_in[1], d_in[2], d_in[3], d_in[8], A, B, G);
        sheaf_k2<<<dim3(NBLK2), dim3(1024), 0, stream>>>(
            d_in[0], d_in[4], d_in[5], d_in[6], d_in[7], A, B, G, partials);
        sheaf_finalize<<<dim3(1), dim3(256), 0, stream>>>(
            d_in[0], d_in[9], d_in[10], d_in[11], d_in[12],
            partials, NBLK2, d_out);
    } else if (d_ws != nullptr && ws_size >= (size_t)WS_R17) {
        // R17-proven fallback: 128-block halo kernel + finalize
        SheafConvolutionalNetwork_81698867905240_kernel<<<dim3(NGRID), dim3(1024), 0, stream>>>(
            d_in[0], d_in[1], d_in[2], d_in[3], d_in[4], d_in[5], d_in[6],
            d_in[7], d_in[8], d_in[9], d_in[10], d_in[11], d_in[12], d_ws);
        sheaf_finalize<<<dim3(1), dim3(256), 0, stream>>>(
            d_in[0], d_in[9], d_in[10], d_in[11], d_in[12],
            (const float*)d_ws, NGRID, d_out);
    } else {
        // R8-proven fallback: single block direct to d_out
        SheafConvolutionalNetwork_81698867905240_kernel<<<dim3(1), dim3(1024), 0, stream>>>(
            d_in[0], d_in[1], d_in[2], d_in[3], d_in[4], d_in[5], d_in[6],
            d_in[7], d_in[8], d_in[9], d_in[10], d_in[11], d_in[12], d_out);
    }

    // Explicit launch-error marker (~12.06 in both dtypes).
    if (hipGetLastError() != hipSuccess)
        (void)hipMemsetAsync(d_out, 0x41, 16, stream);
}

// Round 30
// 52.211 us; speedup vs baseline: 2.7183x; 1.0275x over previous
//
#include <hip/hip_runtime.h>
#include <hip/hip_bf16.h>

// Sheaf CNN on the fixed ring graph (offsets ±1..4 mod 4096, degree 8).
// 3-dispatch pipeline (R24/R29-proven base, 53.6us), 4-nodes-per-wave K1:
//   K1: weights f32 in LDS (proven staging); GEMV by waves 0..3, each
//       owning 4 nodes: per k = 4 b32 broadcasts + 3 b32 weight reads
//       (2-way, free) feeding 12 FMAs -> LDS wave-ops 8192 -> 3584 /CU.
//       Same primitives, same per-node accumulation order => bit-exact.
//   K2: phases 2-4 per 16-node chunk (byte-identical)
//   K3: finalize with Wc1/Wc2 LDS-staged (byte-identical)
// Closed: MFMA-K1 (R26), bf16-packed K1 (R27), b128-bcast K1 (R28),
// fused single-dispatch (R21/R25).
// Fallbacks byte-preserved: ws>=32KB -> R17 128-block halo kernel +
// finalize; else R8 single-block.

#define NN    4096
#define CHK   32            // R17 fallback: chunk nodes
#define EXT   48            // R17 fallback: chunk + 2*8 halo
#define PEXT  40            // R17 fallback: chunk + 2*4 halo
#define NGRID 128           // R17 fallback grid
#define WS_R17 (NGRID * 64u * 4u)

#define NBLK2 256           // pipeline grid (16 nodes/block)
#define PEXT2 24            // 16 + 2*4
#define WS_PIPE ((3u * NN * 64u + NBLK2 * 64u) * 4u)

struct Smem {
    float As[EXT][64];
    float Bs[EXT][64];
    float Gs[EXT][64];
    float Hs[16][64];
    float ps[PEXT][8][2];
    float dinvs[PEXT][2];
    float facs[PEXT][2];
    float red[1024];
    float pooled[64];
    float hid[128];
};

struct SmemK1 {
    float Wa[128][64];    // M1w rows 0..127   (32KB)
    float Wb[128][64];    // M1w rows 128..255 (32KB)
    float Wh[128][64];    // We                (32KB)
    float W2s[64][64];    // W2                (16KB)
    float efs[16][128];   // ef rows           (8KB)
    float Hs[16][64];     // relu(ef@We+be)    (4KB)
};

struct SmemK2 {
    float As[PEXT2][64];
    float Bs[32][64];
    float Gs[32][64];
    float ps[PEXT2][8][2];
    float dinvs[PEXT2][2];
    float facs[PEXT2][2];
    float red[1024];
};

struct SmemFin {
    float Wc1s[64][128];  // 32KB
    float Wc2s[128][8];   // 4KB
    float red[256];
    float pooled[64];
    float hid[128];
};

template <bool F32>
static __device__ __forceinline__ float ldv(const void* p, int i) {
    if constexpr (F32) return ((const float*)p)[i];
    else return __bfloat162float(((const __hip_bfloat16*)p)[i]);
}

static __device__ __forceinline__ float ldr(const void* p, int i, bool f32) {
    if (f32) return ((const float*)p)[i];
    return __bfloat162float(((const __hip_bfloat16*)p)[i]);
}

static __device__ __forceinline__ float blo(unsigned u) {
    return __uint_as_float(u << 16);
}
static __device__ __forceinline__ float bhi(unsigned u) {
    return __uint_as_float(u & 0xFFFF0000u);
}

// ---------- R8/R17-proven halo body (fallback paths) ----------
template <bool F32>
static __device__ void body(Smem& sm,
    const void* ef, const void* We, const void* be, const void* M1w,
    const void* M1b, const void* M2w, const void* M2b, const void* W1,
    const void* W2, const void* Wc1, const void* bc1, const void* Wc2,
    const void* bc2, void* out)
{
    const int t = threadIdx.x;
    const int c = t & 63;
    const int w = t >> 6;
    const int a = (t >> 6) & 1;
    const int ms = t >> 7;

    const float m1b_c = ldv<F32>(M1b, c);
    const float m2w0  = ldv<F32>(M2w, c * 2 + 0);
    const float m2w1  = ldv<F32>(M2w, c * 2 + 1);
    const float m2b0  = ldv<F32>(M2b, 0);
    const float m2b1  = ldv<F32>(M2b, 1);
    const float cs0 = ldv<F32>(W1, 0) + ldv<F32>(W1, 2);
    const float cs1 = ldv<F32>(W1, 1) + ldv<F32>(W1, 3);
    const float bec = ldv<F32>(be, c);

    float accY = 0.f;

    for (int ch = blockIdx.x; ch < NN / CHK; ch += gridDim.x) {
        const int c0 = ch * CHK;
        for (int pp = 0; pp < EXT / 16; ++pp) {
            const int q  = pp * 16 + w;
            const int gi = (c0 - 8 + q) & (NN - 1);
            float aA = 0.f, aB = 0.f, aH = bec;
            #pragma unroll 2
            for (int k = 0; k < 128; ++k) {
                const float ev = ldv<F32>(ef, gi * 128 + k);
                aA += ev * ldv<F32>(M1w, k * 64 + c);
                aB += ev * ldv<F32>(M1w, 8192 + k * 64 + c);
                aH += ev * ldv<F32>(We, k * 64 + c);
            }
            sm.As[q][c] = aA;
            sm.Bs[q][c] = aB;
            sm.Hs[w][c] = fmaxf(aH, 0.f);
            __syncthreads();
            float aG = 0.f;
            #pragma unroll 2
            for (int k = 0; k < 64; ++k)
                aG += sm.Hs[w][k] * ldv<F32>(W2, k * 64 + c);
            sm.Gs[q][c] = aG;
            __syncthreads();
        }
        for (int pi = w; pi < PEXT * 8; pi += 16) {
            const int r  = pi >> 3;
            const int tt = pi & 7;
            const int off = (tt < 4) ? (tt - 4) : (tt - 3);
            const float h = fmaxf(sm.As[r + 4][c] + sm.Bs[r + 4 + off][c] + m1b_c, 0.f);
            float q0 = h * m2w0, q1 = h * m2w1;
            #pragma unroll
            for (int d2 = 32; d2; d2 >>= 1) {
                q0 += __shfl_xor(q0, d2);
                q1 += __shfl_xor(q1, d2);
            }
            if (c == 0) {
                sm.ps[r][tt][0] = q0 + m2b0;
                sm.ps[r][tt][1] = q1 + m2b1;
            }
        }
        __syncthreads();
        if (t < PEXT * 2) {
            const int r = t >> 1, aa = t & 1;
            float s = 0.f;
            #pragma unroll
            for (int tt = 0; tt < 8; ++tt) { const float p = sm.ps[r][tt][aa]; s += p * p; }
            const float dv = 1.f / sqrtf(fmaxf(s + 1e-5f, 1e-6f));
            sm.dinvs[r][aa] = dv;
            sm.facs[r][aa]  = 1.f - dv * dv * s;
        }
        __syncthreads();
        const float csa = a ? cs1 : cs0;
        #pragma unroll
        for (int it = 0; it < 4; ++it) {
            const int m = it * 8 + ms;
            const int r = m + 4;
            const int g = m + 8;
            const float di = sm.dinvs[r][a];
            float v = sm.facs[r][a] * sm.Gs[g][c];
            #pragma unroll
            for (int tt = 0; tt < 8; ++tt) {
                const int off = (tt < 4) ? (tt - 4) : (tt - 3);
                v += di * sm.ps[r + off][7 - tt][a] * sm.ps[r][tt][a]
                        * sm.dinvs[r + off][a] * sm.Gs[g + off][c];
            }
            const float x = csa * v;
            accY += (x > 0.f) ? x : expm1f(x);
        }
        __syncthreads();
    }

    sm.red[t] = accY;
    __syncthreads();

    if (gridDim.x > 1) {
        if (t < 64) {
            float s = 0.f;
            #pragma unroll
            for (int g2 = 0; g2 < 16; ++g2) s += sm.red[(g2 << 6) + t];
            ((float*)out)[blockIdx.x * 64 + t] = s;
        }
        return;
    }

    if (t < 64) {
        float s = 0.f;
        #pragma unroll
        for (int g2 = 0; g2 < 16; ++g2) s += sm.red[(g2 << 6) + t];
        sm.pooled[t] = s * (1.f / 8192.f);
    }
    __syncthreads();
    if (t < 128) {
        float acc = ldv<F32>(bc1, t);
        #pragma unroll 8
        for (int k = 0; k < 64; ++k) acc += sm.pooled[k] * ldv<F32>(Wc1, k * 128 + t);
        sm.hid[t] = fmaxf(acc, 0.f);
    }
    __syncthreads();
    if (t < 8) {
        float acc = ldv<F32>(bc2, t);
        #pragma unroll 8
        for (int k = 0; k < 128; ++k) acc += sm.hid[k] * ldv<F32>(Wc2, k * 8 + t);
        if constexpr (F32) ((float*)out)[t] = acc;
        else ((__hip_bfloat16*)out)[t] = __float2bfloat16(acc);
    }
}

// ---------- K1: node GEMVs, weights in LDS, 4 nodes/wave ----------
template <bool F32>
static __device__ void k1body(SmemK1& sm,
    const void* ef, const void* We, const void* be, const void* M1w,
    const void* W2, float* A, float* B, float* G)
{
    const int t = threadIdx.x, c = t & 63, w = t >> 6;
    const int base = blockIdx.x * 16;

    // ---- stage weights into LDS (R24-proven, all 1024 threads) ----
    if constexpr (F32) {
        for (int idx = t; idx < 128 * 64; idx += 1024) {
            const int k = idx >> 6, cc = idx & 63;
            sm.Wa[k][cc] = ((const float*)M1w)[idx];
            sm.Wb[k][cc] = ((const float*)M1w)[8192 + idx];
            sm.Wh[k][cc] = ((const float*)We)[idx];
        }
        for (int idx = t; idx < 64 * 64; idx += 1024)
            sm.W2s[idx >> 6][idx & 63] = ((const float*)W2)[idx];
        for (int idx = t; idx < 16 * 128; idx += 1024)
            sm.efs[idx >> 7][idx & 127] = ((const float*)ef)[(base << 7) + idx];
    } else {
        for (int j = t; j < 4096; j += 1024) {          // 128 rows x 32 words
            const int k = j >> 5, c2 = (j & 31) * 2;
            const unsigned a = ((const unsigned*)M1w)[j];
            sm.Wa[k][c2] = blo(a);  sm.Wa[k][c2 + 1] = bhi(a);
            const unsigned b = ((const unsigned*)M1w)[4096 + j];
            sm.Wb[k][c2] = blo(b);  sm.Wb[k][c2 + 1] = bhi(b);
            const unsigned h = ((const unsigned*)We)[j];
            sm.Wh[k][c2] = blo(h);  sm.Wh[k][c2 + 1] = bhi(h);
        }
        for (int j = t; j < 2048; j += 1024) {          // 64 rows x 32 words
            const int k = j >> 5, c2 = (j & 31) * 2;
            const unsigned v = ((const unsigned*)W2)[j];
            sm.W2s[k][c2] = blo(v);  sm.W2s[k][c2 + 1] = bhi(v);
        }
        for (int j = t; j < 16 * 64; j += 1024) {       // ef: 16 rows x 64 words
            const int n = j >> 6, kk = (j & 63) * 2;
            const unsigned u = ((const unsigned*)ef)[(base << 6) + j];
            sm.efs[n][kk] = blo(u);  sm.efs[n][kk + 1] = bhi(u);
        }
    }
    __syncthreads();

    // ---- GEMV: waves 0..3, wave w owns nodes 4w..4w+3 ----
    // per k: 3 weight reads (2-way bank, free) + 4 broadcasts -> 12 FMAs
    if (w < 4) {
        const int n0 = w * 4;
        const float bec = ldv<F32>(be, c);
        float aA0 = 0.f, aA1 = 0.f, aA2 = 0.f, aA3 = 0.f;
        float aB0 = 0.f, aB1 = 0.f, aB2 = 0.f, aB3 = 0.f;
        float aH0 = bec, aH1 = bec, aH2 = bec, aH3 = bec;
        #pragma unroll 4
        for (int k = 0; k < 128; ++k) {
            const float wa = sm.Wa[k][c];
            const float wb = sm.Wb[k][c];
            const float wh = sm.Wh[k][c];
            const float e0 = sm.efs[n0 + 0][k];
            const float e1 = sm.efs[n0 + 1][k];
            const float e2 = sm.efs[n0 + 2][k];
            const float e3 = sm.efs[n0 + 3][k];
            aA0 = fmaf(e0, wa, aA0);  aB0 = fmaf(e0, wb, aB0);  aH0 = fmaf(e0, wh, aH0);
            aA1 = fmaf(e1, wa, aA1);  aB1 = fmaf(e1, wb, aB1);  aH1 = fmaf(e1, wh, aH1);
            aA2 = fmaf(e2, wa, aA2);  aB2 = fmaf(e2, wb, aB2);  aH2 = fmaf(e2, wh, aH2);
            aA3 = fmaf(e3, wa, aA3);  aB3 = fmaf(e3, wb, aB3);  aH3 = fmaf(e3, wh, aH3);
        }
        A[((base + n0 + 0) << 6) + c] = aA0;
        A[((base + n0 + 1) << 6) + c] = aA1;
        A[((base + n0 + 2) << 6) + c] = aA2;
        A[((base + n0 + 3) << 6) + c] = aA3;
        B[((base + n0 + 0) << 6) + c] = aB0;
        B[((base + n0 + 1) << 6) + c] = aB1;
        B[((base + n0 + 2) << 6) + c] = aB2;
        B[((base + n0 + 3) << 6) + c] = aB3;
        sm.Hs[n0 + 0][c] = fmaxf(aH0, 0.f);
        sm.Hs[n0 + 1][c] = fmaxf(aH1, 0.f);
        sm.Hs[n0 + 2][c] = fmaxf(aH2, 0.f);
        sm.Hs[n0 + 3][c] = fmaxf(aH3, 0.f);
    }
    __syncthreads();

    // ---- G = relu(H) @ W2: all 16 waves, one node each (R24 pattern) ----
    float aG = 0.f;
    #pragma unroll 8
    for (int k = 0; k < 64; ++k)
        aG = fmaf(sm.Hs[w][k], sm.W2s[k][c], aG);
    G[((base + w) << 6) + c] = aG;
}

__global__ __launch_bounds__(1024) void sheaf_k1(
    const void* ef, const void* We, const void* be, const void* M1w,
    const void* W2, float* A, float* B, float* G)
{
    __shared__ SmemK1 sm;
    __shared__ int flag;
    const int t = threadIdx.x;
    if (t == 0) flag = 0;
    __syncthreads();
    {
        const __hip_bfloat16* efh = (const __hip_bfloat16*)ef;
        bool big = false;
        #pragma unroll
        for (int k = 0; k < 8; ++k) {
            const float v = __bfloat162float(efh[t * 8 + k]);
            big |= !(fabsf(v) < 1e4f);
        }
        if (big) atomicOr(&flag, 1);
    }
    __syncthreads();
    if (flag) k1body<true >(sm, ef, We, be, M1w, W2, A, B, G);
    else      k1body<false>(sm, ef, We, be, M1w, W2, A, B, G);
}

// ---------- K2: sheaf stencil phases 2-4 (R24-proven) ----------
template <bool F32>
static __device__ void k2body(SmemK2& sm,
    const void* M1b, const void* M2w, const void* M2b, const void* W1,
    const float* A, const float* B, const float* G, float* partials)
{
    const int t = threadIdx.x, c = t & 63, w = t >> 6;
    const int base = blockIdx.x * 16;

    for (int idx = t; idx < PEXT2 * 64; idx += 1024) {
        const int r = idx >> 6, cc = idx & 63;
        sm.As[r][cc] = A[(((base - 4 + r) & (NN - 1)) << 6) + cc];
    }
    for (int idx = t; idx < 32 * 64; idx += 1024) {
        const int r = idx >> 6, cc = idx & 63;
        const int gi = ((base - 8 + r) & (NN - 1)) << 6;
        sm.Bs[r][cc] = B[gi + cc];
        sm.Gs[r][cc] = G[gi + cc];
    }
    __syncthreads();

    const float m1b_c = ldv<F32>(M1b, c);
    const float m2w0  = ldv<F32>(M2w, c * 2 + 0);
    const float m2w1  = ldv<F32>(M2w, c * 2 + 1);
    const float m2b0  = ldv<F32>(M2b, 0);
    const float m2b1  = ldv<F32>(M2b, 1);
    const float cs0 = ldv<F32>(W1, 0) + ldv<F32>(W1, 2);
    const float cs1 = ldv<F32>(W1, 1) + ldv<F32>(W1, 3);

    for (int pi = w; pi < PEXT2 * 8; pi += 16) {
        const int r  = pi >> 3;
        const int tt = pi & 7;
        const int off = (tt < 4) ? (tt - 4) : (tt - 3);
        const float h = fmaxf(sm.As[r][c] + sm.Bs[r + 4 + off][c] + m1b_c, 0.f);
        float q0 = h * m2w0, q1 = h * m2w1;
        #pragma unroll
        for (int d2 = 32; d2; d2 >>= 1) {
            q0 += __shfl_xor(q0, d2);
            q1 += __shfl_xor(q1, d2);
        }
        if (c == 0) {
            sm.ps[r][tt][0] = q0 + m2b0;
            sm.ps[r][tt][1] = q1 + m2b1;
        }
    }
    __syncthreads();

    if (t < PEXT2 * 2) {
        const int r = t >> 1, aa = t & 1;
        float s = 0.f;
        #pragma unroll
        for (int tt = 0; tt < 8; ++tt) { const float p = sm.ps[r][tt][aa]; s += p * p; }
        const float dv = 1.f / sqrtf(fmaxf(s + 1e-5f, 1e-6f));
        sm.dinvs[r][aa] = dv;
        sm.facs[r][aa]  = 1.f - dv * dv * s;
    }
    __syncthreads();

    float accY = 0.f;
    #pragma unroll
    for (int it = 0; it < 2; ++it) {
        const int m = it * 8 + (t >> 7);
        const int a = (t >> 6) & 1;
        const int r = m + 4;
        const int g = m + 8;
        const float csa = a ? cs1 : cs0;
        const float di = sm.dinvs[r][a];
        float v = sm.facs[r][a] * sm.Gs[g][c];
        #pragma unroll
        for (int tt = 0; tt < 8; ++tt) {
            const int off = (tt < 4) ? (tt - 4) : (tt - 3);
            v += di * sm.ps[r + off][7 - tt][a] * sm.ps[r][tt][a]
                    * sm.dinvs[r + off][a] * sm.Gs[g + off][c];
        }
        const float x = csa * v;
        accY += (x > 0.f) ? x : expm1f(x);
    }

    sm.red[t] = accY;
    __syncthreads();
    if (t < 64) {
        float s = 0.f;
        #pragma unroll
        for (int g2 = 0; g2 < 16; ++g2) s += sm.red[(g2 << 6) + t];
        partials[blockIdx.x * 64 + t] = s;
    }
}

__global__ __launch_bounds__(1024) void sheaf_k2(
    const void* ef, const void* M1b, const void* M2w, const void* M2b,
    const void* W1, const float* A, const float* B, const float* G,
    float* partials)
{
    __shared__ SmemK2 sm;
    __shared__ int flag;
    const int t = threadIdx.x;
    if (t == 0) flag = 0;
    __syncthreads();
    {
        const __hip_bfloat16* efh = (const __hip_bfloat16*)ef;
        bool big = false;
        #pragma unroll
        for (int k = 0; k < 8; ++k) {
            const float v = __bfloat162float(efh[t * 8 + k]);
            big |= !(fabsf(v) < 1e4f);
        }
        if (big) atomicOr(&flag, 1);
    }
    __syncthreads();
    if (flag) k2body<true >(sm, M1b, M2w, M2b, W1, A, B, G, partials);
    else      k2body<false>(sm, M1b, M2w, M2b, W1, A, B, G, partials);
}

// ---------- finalize: Wc1/Wc2 LDS-staged reduce + classifier ----------
template <bool F32>
static __device__ void finbody(SmemFin& sm,
    const void* Wc1, const void* bc1, const void* Wc2, const void* bc2,
    const float* partials, int nparts, void* out)
{
    const int t = threadIdx.x;

    if constexpr (F32) {
        for (int idx = t; idx < 64 * 128; idx += 256)
            sm.Wc1s[idx >> 7][idx & 127] = ((const float*)Wc1)[idx];
        for (int idx = t; idx < 128 * 8; idx += 256)
            sm.Wc2s[idx >> 3][idx & 7] = ((const float*)Wc2)[idx];
    } else {
        for (int j = t; j < 4096; j += 256) {           // 64 rows x 64 words
            const int k = j >> 6, c2 = (j & 63) * 2;
            const unsigned u = ((const unsigned*)Wc1)[j];
            sm.Wc1s[k][c2] = blo(u);  sm.Wc1s[k][c2 + 1] = bhi(u);
        }
        for (int j = t; j < 512; j += 256) {            // 128 rows x 4 words
            const int k = j >> 2, c2 = (j & 3) * 2;
            const unsigned u = ((const unsigned*)Wc2)[j];
            sm.Wc2s[k][c2] = blo(u);  sm.Wc2s[k][c2 + 1] = bhi(u);
        }
    }

    const int h = t & 63, g = t >> 6;
    float s = 0.f;
    for (int b = g; b < nparts; b += 4) s += partials[b * 64 + h];
    sm.red[t] = s;
    __syncthreads();
    if (t < 64)
        sm.pooled[t] = (sm.red[t] + sm.red[t + 64] + sm.red[t + 128] + sm.red[t + 192])
                       * (1.f / 8192.f);
    __syncthreads();
    if (t < 128) {
        float acc = ldv<F32>(bc1, t);
        #pragma unroll 8
        for (int k = 0; k < 64; ++k) acc = fmaf(sm.pooled[k], sm.Wc1s[k][t], acc);
        sm.hid[t] = fmaxf(acc, 0.f);
    }
    __syncthreads();
    if (t < 8) {
        float acc = ldv<F32>(bc2, t);
        #pragma unroll 8
        for (int k = 0; k < 128; ++k) acc = fmaf(sm.hid[k], sm.Wc2s[k][t], acc);
        if constexpr (F32) ((float*)out)[t] = acc;
        else ((__hip_bfloat16*)out)[t] = __float2bfloat16(acc);
    }
}

__global__ __launch_bounds__(256) void sheaf_finalize(
    const void* ef, const void* Wc1, const void* bc1, const void* Wc2,
    const void* bc2, const float* partials, int nparts, void* out)
{
    __shared__ SmemFin sm;
    __shared__ int flag;
    const int t = threadIdx.x;
    if (t == 0) flag = 0;
    __syncthreads();
    {
        const __hip_bfloat16* efh = (const __hip_bfloat16*)ef;
        bool big = false;
        #pragma unroll
        for (int k = 0; k < 8; ++k) {
            const float v = __bfloat162float(efh[t * 8 + k]);
            big |= !(fabsf(v) < 1e4f);
        }
        if (big) atomicOr(&flag, 1);
    }
    __syncthreads();
    if (flag) finbody<true >(sm, Wc1, bc1, Wc2, bc2, partials, nparts, out);
    else      finbody<false>(sm, Wc1, bc1, Wc2, bc2, partials, nparts, out);
}

__global__ __launch_bounds__(1024) void SheafConvolutionalNetwork_81698867905240_kernel(
    const void* ef, const void* We, const void* be, const void* M1w,
    const void* M1b, const void* M2w, const void* M2b, const void* W1,
    const void* W2, const void* Wc1, const void* bc1, const void* Wc2,
    const void* bc2, void* out)
{
    __shared__ Smem sm;
    __shared__ int flag;
    const int t = threadIdx.x;
    if (t == 0) flag = 0;
    __syncthreads();
    {
        const __hip_bfloat16* efh = (const __hip_bfloat16*)ef;
        bool big = false;
        #pragma unroll
        for (int k = 0; k < 8; ++k) {
            const float v = __bfloat162float(efh[t * 8 + k]);
            big |= !(fabsf(v) < 1e4f);
        }
        if (big) atomicOr(&flag, 1);
    }
    __syncthreads();
    if (flag)
        body<true >(sm, ef, We, be, M1w, M1b, M2w, M2b, W1, W2, Wc1, bc1, Wc2, bc2, out);
    else
        body<false>(sm, ef, We, be, M1w, M1b, M2w, M2b, W1, W2, Wc1, bc1, Wc2, bc2, out);
}

extern "C" void kernel_launch(void* const* d_in, const int* in_sizes, int n_in,
                              void* d_out, int out_size, void* d_ws, size_t ws_size,
                              hipStream_t stream)
{
    (void)in_sizes; (void)n_in; (void)out_size;
    (void)hipGetLastError();   // clear stale error

    if (d_ws != nullptr && ws_size >= (size_t)WS_PIPE) {
        float* A = (float*)d_ws;
        float* B = A + NN * 64;
        float* G = B + NN * 64;
        float* partials = G + NN * 64;
        sheaf_k1<<<dim3(NBLK2), dim3(1024), 0, stream>>>(
            d_in[0], d_in[1], d_in[2], d_in[3], d_in[8], A, B, G);
        sheaf_k2<<<dim3(NBLK2), dim3(1024), 0, stream>>>(
            d_in[0], d_in[4], d_in[5], d_in[6], d_in[7], A, B, G, partials);
        sheaf_finalize<<<dim3(1), dim3(256), 0, stream>>>(
            d_in[0], d_in[9], d_in[10], d_in[11], d_in[12],
            partials, NBLK2, d_out);
    } else if (d_ws != nullptr && ws_size >= (size_t)WS_R17) {
        // R17-proven fallback: 128-block halo kernel + finalize
        SheafConvolutionalNetwork_81698867905240_kernel<<<dim3(NGRID), dim3(1024), 0, stream>>>(
            d_in[0], d_in[1], d_in[2], d_in[3], d_in[4], d_in[5], d_in[6],
            d_in[7], d_in[8], d_in[9], d_in[10], d_in[11], d_in[12], d_ws);
        sheaf_finalize<<<dim3(1), dim3(256), 0, stream>>>(
            d_in[0], d_in[9], d_in[10], d_in[11], d_in[12],
            (const float*)d_ws, NGRID, d_out);
    } else {
        // R8-proven fallback: single block direct to d_out
        SheafConvolutionalNetwork_81698867905240_kernel<<<dim3(1), dim3(1024), 0, stream>>>(
            d_in[0], d_in[1], d_in[2], d_in[3], d_in[4], d_in[5], d_in[6],
            d_in[7], d_in[8], d_in[9], d_in[10], d_in[11], d_in[12], d_out);
    }

    // Explicit launch-error marker (~12.06 in both dtypes).
    if (hipGetLastError() != hipSuccess)
        (void)hipMemsetAsync(d_out, 0x41, 16, stream);
}